// Round 2
// baseline (2039.217 us; speedup 1.0000x reference)
//
#include <hip/hip_runtime.h>
#include <stdint.h>

#define EMB 128
#define LAYERS 3
#define NGRAPHS 64
#define BN_EPS 1e-5f

typedef short short8 __attribute__((ext_vector_type(8)));
typedef float float4v __attribute__((ext_vector_type(4)));

__device__ __forceinline__ unsigned short f2bf(float f) {
    union { float f; unsigned int i; } v; v.f = f;
    unsigned int x = v.i;
    unsigned int r = x + 0x7FFFu + ((x >> 16) & 1u);
    return (unsigned short)(r >> 16);
}

// f32 -> bf16 (RNE) elementwise, for weight pre-conversion
__global__ __launch_bounds__(256) void conv_bf16(
    const float* __restrict__ in, unsigned short* __restrict__ out, int n)
{
    int i = blockIdx.x * 256 + threadIdx.x;
    if (i < n) out[i] = f2bf(in[i]);
}

// ---------------------------------------------------------------------------
// GEMM: C[M,Ntot] = epilogue(A[M,K] @ B[Ntot,K]^T + bias)
// B bf16 row-major [n][k]. A f32 (converted in-reg) or bf16. MFMA 16x16x32.
// Block 256 = 4 waves; wave w: rows [blk.x*64 + w*16, +16) x cols [blk.y*64,+64)
// ---------------------------------------------------------------------------
template<int K, bool A_IS_BF16, bool RELU, bool OUT_BF16>
__global__ __launch_bounds__(256) void gemm_bt(
    const void* __restrict__ Av, const unsigned short* __restrict__ B,
    const float* __restrict__ bias, void* __restrict__ Cv,
    int M, int Ntot)
{
    const int wave = threadIdx.x >> 6;
    const int lane = threadIdx.x & 63;
    const int q    = lane >> 4;
    const int ln   = lane & 15;
    const int m_base = blockIdx.x * 64 + wave * 16;
    const int n_base = blockIdx.y * 64;

    float4v acc[4];
#pragma unroll
    for (int i = 0; i < 4; ++i) acc[i] = (float4v){0.f, 0.f, 0.f, 0.f};

    int mrow = m_base + ln;
    if (mrow >= M) mrow = M - 1;   // clamp loads; stores guarded

    const int KSTEPS = K / 32;
#pragma unroll
    for (int ks = 0; ks < KSTEPS; ++ks) {
        const int k0 = ks * 32 + q * 8;
        short8 afrag;
        if constexpr (A_IS_BF16) {
            const unsigned short* A = (const unsigned short*)Av;
            afrag = *reinterpret_cast<const short8*>(A + (size_t)mrow * K + k0);
        } else {
            const float* A = (const float*)Av;
            const float4v* p = reinterpret_cast<const float4v*>(A + (size_t)mrow * K + k0);
            float4v f0 = p[0], f1 = p[1];
            afrag[0] = (short)f2bf(f0[0]); afrag[1] = (short)f2bf(f0[1]);
            afrag[2] = (short)f2bf(f0[2]); afrag[3] = (short)f2bf(f0[3]);
            afrag[4] = (short)f2bf(f1[0]); afrag[5] = (short)f2bf(f1[1]);
            afrag[6] = (short)f2bf(f1[2]); afrag[7] = (short)f2bf(f1[3]);
        }
#pragma unroll
        for (int nt = 0; nt < 4; ++nt) {
            const short8 bfrag = *reinterpret_cast<const short8*>(
                B + (size_t)(n_base + nt * 16 + ln) * K + k0);
            acc[nt] = __builtin_amdgcn_mfma_f32_16x16x32_bf16(afrag, bfrag, acc[nt], 0, 0, 0);
        }
    }

#pragma unroll
    for (int nt = 0; nt < 4; ++nt) {
        const int n = n_base + nt * 16 + ln;
        const float bv = bias[n];
#pragma unroll
        for (int r = 0; r < 4; ++r) {
            const int m = m_base + q * 4 + r;
            if (m < M) {
                float v = acc[nt][r] + bv;
                if constexpr (RELU) v = v > 0.f ? v : 0.f;
                if constexpr (OUT_BF16)
                    ((unsigned short*)Cv)[(size_t)m * Ntot + n] = f2bf(v);
                else
                    ((float*)Cv)[(size_t)m * Ntot + n] = v;
            }
        }
    }
}

// ---------------------------------------------------------------------------
// aggr[n][c] = h[n][c] + be[c]   (self-loop message), float4 vectorized
// ---------------------------------------------------------------------------
__global__ __launch_bounds__(256) void init_aggr(
    const float* __restrict__ h, const float* __restrict__ be,
    float* __restrict__ aggr, int total4)
{
    int tid = blockIdx.x * 256 + threadIdx.x;
    int c4 = (tid * 4) & 127;  // invariant: stride*4 % 128 == 0
    float b0 = be[c4], b1 = be[c4 + 1], b2 = be[c4 + 2], b3 = be[c4 + 3];
    int stride = gridDim.x * 256;
    for (int i = tid; i < total4; i += stride) {
        float4v v = reinterpret_cast<const float4v*>(h)[i];
        v[0] += b0; v[1] += b1; v[2] += b2; v[3] += b3;
        reinterpret_cast<float4v*>(aggr)[i] = v;
    }
}

// ---------------------------------------------------------------------------
// Edge scatter: aggr[dst][c] += h[src][c] + (edge_attr[e] . We[c][:]) + be[c]
// thread = (edge, channel); block 256 = 2 edges x 128 channels; We reg-cached
// ---------------------------------------------------------------------------
__global__ __launch_bounds__(256) void edge_kernel(
    const int* __restrict__ ei, const float* __restrict__ eattr,
    const float* __restrict__ We, const float* __restrict__ be,
    const float* __restrict__ h, float* __restrict__ aggr, int E)
{
    const int c = threadIdx.x & 127;
    const int sub = threadIdx.x >> 7;
    float w[16];
#pragma unroll
    for (int k = 0; k < 16; ++k) w[k] = We[c * 16 + k];
    const float b = be[c];

    const int stride = gridDim.x * 2;
    for (int e = blockIdx.x * 2 + sub; e < E; e += stride) {
        const int src = ei[e];
        const int dst = ei[E + e];
        const float4v* ap = reinterpret_cast<const float4v*>(eattr + (size_t)e * 16);
        float4v a0 = ap[0], a1 = ap[1], a2 = ap[2], a3 = ap[3];
        float ea[16] = {a0[0],a0[1],a0[2],a0[3], a1[0],a1[1],a1[2],a1[3],
                        a2[0],a2[1],a2[2],a2[3], a3[0],a3[1],a3[2],a3[3]};
        float emb = b;
#pragma unroll
        for (int k = 0; k < 16; ++k) emb += w[k] * ea[k];
        const float val = h[(size_t)src * 128 + c] + emb;
        atomicAdd(&aggr[(size_t)dst * 128 + c], val);
    }
}

// ---------------------------------------------------------------------------
// BatchNorm pass 1: per-channel sum / sumsq (block partials -> atomics)
// ---------------------------------------------------------------------------
__global__ __launch_bounds__(256) void bn_stats(
    const float* __restrict__ h2, float* __restrict__ sums,
    float* __restrict__ sumsq, int N)
{
    const int c = threadIdx.x & 127;
    const int sub = threadIdx.x >> 7;
    float s = 0.f, s2 = 0.f;
    const int stride = gridDim.x * 2;
    for (int n = blockIdx.x * 2 + sub; n < N; n += stride) {
        float v = h2[(size_t)n * 128 + c];
        s += v; s2 += v * v;
    }
    __shared__ float ls[256], ls2[256];
    ls[threadIdx.x] = s; ls2[threadIdx.x] = s2;
    __syncthreads();
    if (threadIdx.x < 128) {
        s  = ls[threadIdx.x]  + ls[threadIdx.x + 128];
        s2 = ls2[threadIdx.x] + ls2[threadIdx.x + 128];
        atomicAdd(&sums[c], s);
        atomicAdd(&sumsq[c], s2);
    }
}

// ---------------------------------------------------------------------------
// BatchNorm pass 2: h = gamma*(h2-mu)*rsqrt(var+eps)+beta (+optional relu)
// ---------------------------------------------------------------------------
__global__ __launch_bounds__(256) void bn_apply(
    const float* __restrict__ h2, const float* __restrict__ sums,
    const float* __restrict__ sumsq, const float* __restrict__ gamma,
    const float* __restrict__ beta, float* __restrict__ h,
    int total4, float invN, int relu)
{
    int tid = blockIdx.x * 256 + threadIdx.x;
    int c4 = (tid * 4) & 127;
    float sc[4], sh[4];
#pragma unroll
    for (int j = 0; j < 4; ++j) {
        int c = c4 + j;
        float mu = sums[c] * invN;
        float var = sumsq[c] * invN - mu * mu;
        float s = gamma[c] * rsqrtf(fmaxf(var, 0.f) + BN_EPS);
        sc[j] = s;
        sh[j] = beta[c] - mu * s;
    }
    int stride = gridDim.x * 256;
    for (int i = tid; i < total4; i += stride) {
        float4v v = reinterpret_cast<const float4v*>(h2)[i];
#pragma unroll
        for (int j = 0; j < 4; ++j) {
            float x = sc[j] * v[j] + sh[j];
            if (relu) x = x > 0.f ? x : 0.f;
            v[j] = x;
        }
        reinterpret_cast<float4v*>(h)[i] = v;
    }
}

// ---------------------------------------------------------------------------
// Global mean-pool (sums + counts via atomics)
// ---------------------------------------------------------------------------
__global__ __launch_bounds__(256) void pool_kernel(
    const float* __restrict__ h, const int* __restrict__ batch,
    float* __restrict__ pooled, float* __restrict__ cnt, int N)
{
    const int c = threadIdx.x & 127;
    const int sub = threadIdx.x >> 7;
    const int stride = gridDim.x * 2;
    for (int n = blockIdx.x * 2 + sub; n < N; n += stride) {
        int g = batch[n];
        atomicAdd(&pooled[(size_t)g * 128 + c], h[(size_t)n * 128 + c]);
        if (c == 0) atomicAdd(&cnt[g], 1.0f);
    }
}

// ---------------------------------------------------------------------------
// Head: out[g] = (pooled[g]/max(cnt,1)) . Wp + bp     (64 graphs, f32 out)
// ---------------------------------------------------------------------------
__global__ __launch_bounds__(128) void head_kernel(
    const float* __restrict__ pooled, const float* __restrict__ cnt,
    const float* __restrict__ Wp, const float* __restrict__ bp,
    float* __restrict__ out)
{
    const int g = blockIdx.x;
    const int c = threadIdx.x;
    float val = pooled[(size_t)g * 128 + c] / fmaxf(cnt[g], 1.f) * Wp[c];
    __shared__ float red[128];
    red[c] = val;
    __syncthreads();
    for (int s = 64; s > 0; s >>= 1) {
        if (c < s) red[c] += red[c + s];
        __syncthreads();
    }
    if (c == 0) out[g] = red[0] + bp[0];
}

// ---------------------------------------------------------------------------
extern "C" void kernel_launch(void* const* d_in, const int* in_sizes, int n_in,
                              void* d_out, int out_size, void* d_ws, size_t ws_size,
                              hipStream_t stream)
{
    const float* x     = (const float*)d_in[0];
    const float* eattr = (const float*)d_in[1];
    const float* W0    = (const float*)d_in[2];
    const float* b0    = (const float*)d_in[3];
    const float* We    = (const float*)d_in[4];
    const float* be    = (const float*)d_in[5];
    const float* W1    = (const float*)d_in[6];
    const float* b1    = (const float*)d_in[7];
    const float* W2    = (const float*)d_in[8];
    const float* b2    = (const float*)d_in[9];
    const float* gamma = (const float*)d_in[10];
    const float* beta  = (const float*)d_in[11];
    const float* Wp    = (const float*)d_in[12];
    const float* bp    = (const float*)d_in[13];
    const int* ei    = (const int*)d_in[14];
    const int* batch = (const int*)d_in[15];

    const int N = in_sizes[0] / 32;   // 50000
    const int E = in_sizes[1] / 16;   // 800000

    char* ws = (char*)d_ws;
    float* hbuf  = (float*)ws;                              // N*128 f32 (alias: Y bf16 [N,256])
    float* aggr  = (float*)(ws + (size_t)N * 128 * 4);      // N*128 f32 (alias: h2)
    float* sums  = (float*)(ws + (size_t)N * 128 * 8);      // 128
    float* sumsq = sums + 128;                              // 128
    float* pooled = sums + 256;                             // 64*128
    float* cnt    = pooled + 64 * 128;                      // 64
    unsigned short* W0bf = (unsigned short*)(cnt + 64);     // 128*32
    unsigned short* W1bf = W0bf + 128 * 32;                 // 3*256*128
    unsigned short* W2bf = W1bf + 3 * 256 * 128;            // 3*128*256

    const dim3 blk(256);
    const int mblocks = (N + 63) / 64;
    const int total4 = N * 32;

    // Pre-convert weights to bf16 (RNE)
    conv_bf16<<<dim3(16), blk, 0, stream>>>(W0, W0bf, 128 * 32);
    conv_bf16<<<dim3(384), blk, 0, stream>>>(W1, W1bf, 3 * 256 * 128);
    conv_bf16<<<dim3(384), blk, 0, stream>>>(W2, W2bf, 3 * 128 * 256);

    // h = x @ W0^T + b0   (A f32 [N,32] converted in-reg, B=W0bf [128][32])
    gemm_bt<32, false, false, false><<<dim3(mblocks, 2), blk, 0, stream>>>(
        x, W0bf, b0, (void*)hbuf, N, 128);

    for (int l = 0; l < LAYERS; ++l) {
        hipMemsetAsync(sums, 0, 256 * 4, stream);
        init_aggr<<<dim3(1024), blk, 0, stream>>>(hbuf, be + l * 128, aggr, total4);
        edge_kernel<<<dim3(2048), blk, 0, stream>>>(
            ei, eattr, We + l * 128 * 16, be + l * 128, hbuf, aggr, E);
        // Y = relu(aggr @ W1^T + b1) -> bf16 [N,256], stored in hbuf region
        gemm_bt<128, false, true, true><<<dim3(mblocks, 4), blk, 0, stream>>>(
            aggr, W1bf + l * 256 * 128, b1 + l * 256, (void*)hbuf, N, 256);
        // h2 = Y @ W2^T + b2 -> f32 [N,128], stored in aggr region
        gemm_bt<256, true, false, false><<<dim3(mblocks, 2), blk, 0, stream>>>(
            hbuf, W2bf + l * 128 * 256, b2 + l * 128, (void*)aggr, N, 128);
        bn_stats<<<dim3(512), blk, 0, stream>>>(aggr, sums, sumsq, N);
        bn_apply<<<dim3(1024), blk, 0, stream>>>(
            aggr, sums, sumsq, gamma + l * 128, beta + l * 128, hbuf,
            total4, 1.0f / (float)N, (l < LAYERS - 1) ? 1 : 0);
    }

    hipMemsetAsync(pooled, 0, (64 * 128 + 64) * 4, stream);
    pool_kernel<<<dim3(1024), blk, 0, stream>>>(hbuf, batch, pooled, cnt, N);
    head_kernel<<<dim3(64), dim3(128), 0, stream>>>(pooled, cnt, Wp, bp,
                                                    (float*)d_out);
}

// Round 3
// 1395.832 us; speedup vs baseline: 1.4609x; 1.4609x over previous
//
#include <hip/hip_runtime.h>
#include <stdint.h>

#define EMB 128
#define LAYERS 3
#define NGRAPHS 64
#define BN_EPS 1e-5f

typedef short short8 __attribute__((ext_vector_type(8)));
typedef float float4v __attribute__((ext_vector_type(4)));

__device__ __forceinline__ unsigned short f2bf(float f) {
    union { float f; unsigned int i; } v; v.f = f;
    unsigned int x = v.i;
    unsigned int r = x + 0x7FFFu + ((x >> 16) & 1u);
    return (unsigned short)(r >> 16);
}

// f32 -> bf16 (RNE) elementwise, for weight pre-conversion
__global__ __launch_bounds__(256) void conv_bf16(
    const float* __restrict__ in, unsigned short* __restrict__ out, int n)
{
    int i = blockIdx.x * 256 + threadIdx.x;
    if (i < n) out[i] = f2bf(in[i]);
}

// ---------------------------------------------------------------------------
// GEMM: C[M,Ntot] = epilogue(A[M,K] @ B[Ntot,K]^T + bias)
// B bf16 row-major [n][k]. A f32 (converted in-reg) or bf16. MFMA 16x16x32.
// ---------------------------------------------------------------------------
template<int K, bool A_IS_BF16, bool RELU, bool OUT_BF16>
__global__ __launch_bounds__(256) void gemm_bt(
    const void* __restrict__ Av, const unsigned short* __restrict__ B,
    const float* __restrict__ bias, void* __restrict__ Cv,
    int M, int Ntot)
{
    const int wave = threadIdx.x >> 6;
    const int lane = threadIdx.x & 63;
    const int q    = lane >> 4;
    const int ln   = lane & 15;
    const int m_base = blockIdx.x * 64 + wave * 16;
    const int n_base = blockIdx.y * 64;

    float4v acc[4];
#pragma unroll
    for (int i = 0; i < 4; ++i) acc[i] = (float4v){0.f, 0.f, 0.f, 0.f};

    int mrow = m_base + ln;
    if (mrow >= M) mrow = M - 1;   // clamp loads; stores guarded

    const int KSTEPS = K / 32;
#pragma unroll
    for (int ks = 0; ks < KSTEPS; ++ks) {
        const int k0 = ks * 32 + q * 8;
        short8 afrag;
        if constexpr (A_IS_BF16) {
            const unsigned short* A = (const unsigned short*)Av;
            afrag = *reinterpret_cast<const short8*>(A + (size_t)mrow * K + k0);
        } else {
            const float* A = (const float*)Av;
            const float4v* p = reinterpret_cast<const float4v*>(A + (size_t)mrow * K + k0);
            float4v f0 = p[0], f1 = p[1];
            afrag[0] = (short)f2bf(f0[0]); afrag[1] = (short)f2bf(f0[1]);
            afrag[2] = (short)f2bf(f0[2]); afrag[3] = (short)f2bf(f0[3]);
            afrag[4] = (short)f2bf(f1[0]); afrag[5] = (short)f2bf(f1[1]);
            afrag[6] = (short)f2bf(f1[2]); afrag[7] = (short)f2bf(f1[3]);
        }
#pragma unroll
        for (int nt = 0; nt < 4; ++nt) {
            const short8 bfrag = *reinterpret_cast<const short8*>(
                B + (size_t)(n_base + nt * 16 + ln) * K + k0);
            acc[nt] = __builtin_amdgcn_mfma_f32_16x16x32_bf16(afrag, bfrag, acc[nt], 0, 0, 0);
        }
    }

#pragma unroll
    for (int nt = 0; nt < 4; ++nt) {
        const int n = n_base + nt * 16 + ln;
        const float bv = bias[n];
#pragma unroll
        for (int r = 0; r < 4; ++r) {
            const int m = m_base + q * 4 + r;
            if (m < M) {
                float v = acc[nt][r] + bv;
                if constexpr (RELU) v = v > 0.f ? v : 0.f;
                if constexpr (OUT_BF16)
                    ((unsigned short*)Cv)[(size_t)m * Ntot + n] = f2bf(v);
                else
                    ((float*)Cv)[(size_t)m * Ntot + n] = v;
            }
        }
    }
}

// ---------------------------------------------------------------------------
// CSR build: histogram of dst
// ---------------------------------------------------------------------------
__global__ __launch_bounds__(256) void hist_kernel(
    const int* __restrict__ ei, int* __restrict__ deg_cnt, int E)
{
    int e = blockIdx.x * 256 + threadIdx.x;
    if (e < E) atomicAdd(&deg_cnt[ei[E + e]], 1);
}

// single-block exclusive scan: rowptr[0..n] and wp copy
__global__ __launch_bounds__(1024) void scan_kernel(
    const int* __restrict__ deg, int* __restrict__ rowptr,
    int* __restrict__ wp, int n)
{
    const int T = 1024;
    const int tid = threadIdx.x;
    const int per = (n + T - 1) / T;
    const int start = tid * per;
    const int end = min(start + per, n);
    int sum = 0;
    for (int i = start; i < end; ++i) sum += deg[i];

    // block exclusive scan of per-thread sums (wave shfl + LDS)
    const int lane = tid & 63, wv = tid >> 6;
    int v = sum;
#pragma unroll
    for (int off = 1; off < 64; off <<= 1) {
        int t = __shfl_up(v, off);
        if (lane >= off) v += t;
    }
    __shared__ int wsum[16];
    if (lane == 63) wsum[wv] = v;
    __syncthreads();
    if (wv == 0 && lane < 16) {
        int wvv = wsum[lane];
#pragma unroll
        for (int off = 1; off < 16; off <<= 1) {
            int t = __shfl_up(wvv, off);
            if (lane >= off) wvv += t;
        }
        wsum[lane] = wvv;
    }
    __syncthreads();
    const int waveoff = (wv == 0) ? 0 : wsum[wv - 1];
    int run = waveoff + v - sum;  // exclusive prefix for this thread
    for (int i = start; i < end; ++i) {
        rowptr[i] = run; wp[i] = run;
        run += deg[i];
    }
    if (tid == T - 1) rowptr[n] = run;  // total
}

// fill adjacency: adj[slot] = (src, edge_id), slots grouped by dst
__global__ __launch_bounds__(256) void fill_kernel(
    const int* __restrict__ ei, int* __restrict__ wp,
    int2* __restrict__ adj, int E)
{
    int e = blockIdx.x * 256 + threadIdx.x;
    if (e < E) {
        int dst = ei[E + e];
        int slot = atomicAdd(&wp[dst], 1);
        adj[slot] = make_int2(ei[e], e);
    }
}

// ---------------------------------------------------------------------------
// Gather aggregation (replaces atomic edge scatter + init):
// aggr[n] = h[n] + be*(deg+1) + We·(Σ_in eattr) + Σ_in h[src]
// One wave per node; lane holds channels 2*lane, 2*lane+1 (float2).
// ---------------------------------------------------------------------------
__global__ __launch_bounds__(256) void aggregate_kernel(
    const float2* __restrict__ h2p, const int2* __restrict__ adj,
    const int* __restrict__ rowptr, const float* __restrict__ eattr,
    const float* __restrict__ We, const float* __restrict__ be,
    float2* __restrict__ aggr2, int N)
{
    const int lane = threadIdx.x & 63;
    const int gwave = (blockIdx.x * 256 + threadIdx.x) >> 6;
    const int nwaves = (gridDim.x * 256) >> 6;
    const int c0 = 2 * lane, c1 = c0 + 1;

    float w0[16], w1[16];
#pragma unroll
    for (int k = 0; k < 16; ++k) { w0[k] = We[c0 * 16 + k]; w1[k] = We[c1 * 16 + k]; }
    const float b0 = be[c0], b1 = be[c1];

    for (int n = gwave; n < N; n += nwaves) {
        const int s = rowptr[n], e = rowptr[n + 1];
        float2 acc = h2p[(size_t)n * 64 + lane];   // self-loop h
        float sea = 0.f;                           // lanes 0..15: sum eattr[.,lane]
        for (int p = s; p < e; ++p) {
            const int2 se = adj[p];
            const float2 hv = h2p[(size_t)se.x * 64 + lane];
            acc.x += hv.x; acc.y += hv.y;
            if (lane < 16) sea += eattr[(size_t)se.y * 16 + lane];
        }
        const float degp1 = (float)(e - s + 1);
        float d0 = b0 * degp1, d1 = b1 * degp1;
#pragma unroll
        for (int k = 0; k < 16; ++k) {
            const float sk = __shfl(sea, k);
            d0 += w0[k] * sk; d1 += w1[k] * sk;
        }
        acc.x += d0; acc.y += d1;
        aggr2[(size_t)n * 64 + lane] = acc;
    }
}

// ---------------------------------------------------------------------------
// BatchNorm pass 1: per-channel sum / sumsq (block partials -> atomics)
// ---------------------------------------------------------------------------
__global__ __launch_bounds__(256) void bn_stats(
    const float* __restrict__ h2, float* __restrict__ sums,
    float* __restrict__ sumsq, int N)
{
    const int c = threadIdx.x & 127;
    const int sub = threadIdx.x >> 7;
    float s = 0.f, s2 = 0.f;
    const int stride = gridDim.x * 2;
    for (int n = blockIdx.x * 2 + sub; n < N; n += stride) {
        float v = h2[(size_t)n * 128 + c];
        s += v; s2 += v * v;
    }
    __shared__ float ls[256], ls2[256];
    ls[threadIdx.x] = s; ls2[threadIdx.x] = s2;
    __syncthreads();
    if (threadIdx.x < 128) {
        s  = ls[threadIdx.x]  + ls[threadIdx.x + 128];
        s2 = ls2[threadIdx.x] + ls2[threadIdx.x + 128];
        atomicAdd(&sums[c], s);
        atomicAdd(&sumsq[c], s2);
    }
}

// ---------------------------------------------------------------------------
// BatchNorm pass 2: h = gamma*(h2-mu)*rsqrt(var+eps)+beta (+optional relu)
// ---------------------------------------------------------------------------
__global__ __launch_bounds__(256) void bn_apply(
    const float* __restrict__ h2, const float* __restrict__ sums,
    const float* __restrict__ sumsq, const float* __restrict__ gamma,
    const float* __restrict__ beta, float* __restrict__ h,
    int total4, float invN, int relu)
{
    int tid = blockIdx.x * 256 + threadIdx.x;
    int c4 = (tid * 4) & 127;
    float sc[4], sh[4];
#pragma unroll
    for (int j = 0; j < 4; ++j) {
        int c = c4 + j;
        float mu = sums[c] * invN;
        float var = sumsq[c] * invN - mu * mu;
        float s = gamma[c] * rsqrtf(fmaxf(var, 0.f) + BN_EPS);
        sc[j] = s;
        sh[j] = beta[c] - mu * s;
    }
    int stride = gridDim.x * 256;
    for (int i = tid; i < total4; i += stride) {
        float4v v = reinterpret_cast<const float4v*>(h2)[i];
#pragma unroll
        for (int j = 0; j < 4; ++j) {
            float x = sc[j] * v[j] + sh[j];
            if (relu) x = x > 0.f ? x : 0.f;
            v[j] = x;
        }
        reinterpret_cast<float4v*>(h)[i] = v;
    }
}

// ---------------------------------------------------------------------------
// Fused mean-pool + head. batch is sorted: block g binary-searches its
// segment, reduces without atomics, applies Wp dot + bp.
// ---------------------------------------------------------------------------
__global__ __launch_bounds__(256) void pool_head(
    const float* __restrict__ h, const int* __restrict__ batch,
    const float* __restrict__ Wp, const float* __restrict__ bp,
    float* __restrict__ out, int N)
{
    const int g = blockIdx.x;
    __shared__ int sb[2];
    if (threadIdx.x < 2) {
        int target = g + threadIdx.x;
        int lo = 0, hi = N;
        while (lo < hi) {
            int mid = (lo + hi) >> 1;
            if (batch[mid] < target) lo = mid + 1; else hi = mid;
        }
        sb[threadIdx.x] = lo;
    }
    __syncthreads();
    const int s = sb[0], e = sb[1];
    const int c = threadIdx.x & 127;
    const int sub = threadIdx.x >> 7;
    float acc = 0.f;
    for (int n = s + sub; n < e; n += 2) acc += h[(size_t)n * 128 + c];
    __shared__ float red[256];
    red[threadIdx.x] = acc;
    __syncthreads();
    if (threadIdx.x < 128) {
        float v = red[threadIdx.x] + red[threadIdx.x + 128];
        red[threadIdx.x] = v / fmaxf((float)(e - s), 1.f) * Wp[c];
    }
    __syncthreads();
    for (int st = 64; st > 0; st >>= 1) {
        if (threadIdx.x < st) red[threadIdx.x] += red[threadIdx.x + st];
        __syncthreads();
    }
    if (threadIdx.x == 0) out[g] = red[0] + bp[0];
}

// ---------------------------------------------------------------------------
extern "C" void kernel_launch(void* const* d_in, const int* in_sizes, int n_in,
                              void* d_out, int out_size, void* d_ws, size_t ws_size,
                              hipStream_t stream)
{
    const float* x     = (const float*)d_in[0];
    const float* eattr = (const float*)d_in[1];
    const float* W0    = (const float*)d_in[2];
    const float* b0    = (const float*)d_in[3];
    const float* We    = (const float*)d_in[4];
    const float* be    = (const float*)d_in[5];
    const float* W1    = (const float*)d_in[6];
    const float* b1    = (const float*)d_in[7];
    const float* W2    = (const float*)d_in[8];
    const float* b2    = (const float*)d_in[9];
    const float* gamma = (const float*)d_in[10];
    const float* beta  = (const float*)d_in[11];
    const float* Wp    = (const float*)d_in[12];
    const float* bp    = (const float*)d_in[13];
    const int* ei    = (const int*)d_in[14];
    const int* batch = (const int*)d_in[15];

    const int N = in_sizes[0] / 32;   // 50000
    const int E = in_sizes[1] / 16;   // 800000

    char* ws = (char*)d_ws;
    size_t off = 0;
    auto alloc = [&](size_t bytes) { char* p = ws + off; off += (bytes + 255) & ~(size_t)255; return p; };
    float* hbuf  = (float*)alloc((size_t)N * 128 * 4);   // alias: Y bf16 [N,256]
    float* aggr  = (float*)alloc((size_t)N * 128 * 4);   // alias: h2
    float* sums  = (float*)alloc(256 * 4);               // sums(128) + sumsq(128)
    float* sumsq = sums + 128;
    unsigned short* W0bf = (unsigned short*)alloc(128 * 32 * 2);
    unsigned short* W1bf = (unsigned short*)alloc(3 * 256 * 128 * 2);
    unsigned short* W2bf = (unsigned short*)alloc(3 * 128 * 256 * 2);
    int* deg_cnt = (int*)alloc((size_t)N * 4);
    int* rowptr  = (int*)alloc(((size_t)N + 1) * 4);
    int* wp      = (int*)alloc((size_t)N * 4);
    int2* adj    = (int2*)alloc((size_t)E * 8);

    const dim3 blk(256);
    const int mblocks = (N + 63) / 64;
    const int total4 = N * 32;
    const int eblocks = (E + 255) / 256;

    // --- CSR build (once per call, reused by all 3 layers) ---
    hipMemsetAsync(deg_cnt, 0, (size_t)N * 4, stream);
    hist_kernel<<<dim3(eblocks), blk, 0, stream>>>(ei, deg_cnt, E);
    scan_kernel<<<dim3(1), dim3(1024), 0, stream>>>(deg_cnt, rowptr, wp, N);
    fill_kernel<<<dim3(eblocks), blk, 0, stream>>>(ei, wp, adj, E);

    // --- weight pre-conversion to bf16 ---
    conv_bf16<<<dim3(16), blk, 0, stream>>>(W0, W0bf, 128 * 32);
    conv_bf16<<<dim3(384), blk, 0, stream>>>(W1, W1bf, 3 * 256 * 128);
    conv_bf16<<<dim3(384), blk, 0, stream>>>(W2, W2bf, 3 * 128 * 256);

    // h = x @ W0^T + b0
    gemm_bt<32, false, false, false><<<dim3(mblocks, 2), blk, 0, stream>>>(
        x, W0bf, b0, (void*)hbuf, N, 128);

    for (int l = 0; l < LAYERS; ++l) {
        hipMemsetAsync(sums, 0, 256 * 4, stream);
        aggregate_kernel<<<dim3(2048), blk, 0, stream>>>(
            (const float2*)hbuf, adj, rowptr, eattr,
            We + l * 128 * 16, be + l * 128, (float2*)aggr, N);
        // Y = relu(aggr @ W1^T + b1) -> bf16 [N,256] in hbuf region
        gemm_bt<128, false, true, true><<<dim3(mblocks, 4), blk, 0, stream>>>(
            aggr, W1bf + l * 256 * 128, b1 + l * 256, (void*)hbuf, N, 256);
        // h2 = Y @ W2^T + b2 -> f32 [N,128] in aggr region
        gemm_bt<256, true, false, false><<<dim3(mblocks, 2), blk, 0, stream>>>(
            hbuf, W2bf + l * 128 * 256, b2 + l * 128, (void*)aggr, N, 128);
        bn_stats<<<dim3(512), blk, 0, stream>>>(aggr, sums, sumsq, N);
        bn_apply<<<dim3(1024), blk, 0, stream>>>(
            aggr, sums, sumsq, gamma + l * 128, beta + l * 128, hbuf,
            total4, 1.0f / (float)N, (l < LAYERS - 1) ? 1 : 0);
    }

    pool_head<<<dim3(NGRAPHS), blk, 0, stream>>>(hbuf, batch, Wp, bp,
                                                 (float*)d_out, N);
}

// Round 4
// 1136.412 us; speedup vs baseline: 1.7944x; 1.2283x over previous
//
#include <hip/hip_runtime.h>
#include <stdint.h>

#define EMB 128
#define LAYERS 3
#define NGRAPHS 64
#define BN_EPS 1e-5f

typedef short short8 __attribute__((ext_vector_type(8)));
typedef float float4v __attribute__((ext_vector_type(4)));

__device__ __forceinline__ unsigned short f2bf(float f) {
    union { float f; unsigned int i; } v; v.f = f;
    unsigned int x = v.i;
    unsigned int r = x + 0x7FFFu + ((x >> 16) & 1u);
    return (unsigned short)(r >> 16);
}
// ushort2-in-uint bf16 pair -> floats
__device__ __forceinline__ float bflo(unsigned int u) {
    union { unsigned int i; float f; } v; v.i = u << 16; return v.f;
}
__device__ __forceinline__ float bfhi(unsigned int u) {
    union { unsigned int i; float f; } v; v.i = u & 0xffff0000u; return v.f;
}
__device__ __forceinline__ unsigned int packbf(float a, float b) {
    return (unsigned int)f2bf(a) | ((unsigned int)f2bf(b) << 16);
}

// f32 -> bf16 (RNE) elementwise, for weight pre-conversion
__global__ __launch_bounds__(256) void conv_bf16(
    const float* __restrict__ in, unsigned short* __restrict__ out, int n)
{
    int i = blockIdx.x * 256 + threadIdx.x;
    if (i < n) out[i] = f2bf(in[i]);
}

// ---------------------------------------------------------------------------
// GEMM: C[M,Ntot] = epilogue(A[M,K] @ B[Ntot,K]^T + bias)
// ---------------------------------------------------------------------------
template<int K, bool A_IS_BF16, bool RELU, bool OUT_BF16>
__global__ __launch_bounds__(256) void gemm_bt(
    const void* __restrict__ Av, const unsigned short* __restrict__ B,
    const float* __restrict__ bias, void* __restrict__ Cv,
    int M, int Ntot)
{
    const int wave = threadIdx.x >> 6;
    const int lane = threadIdx.x & 63;
    const int q    = lane >> 4;
    const int ln   = lane & 15;
    const int m_base = blockIdx.x * 64 + wave * 16;
    const int n_base = blockIdx.y * 64;

    float4v acc[4];
#pragma unroll
    for (int i = 0; i < 4; ++i) acc[i] = (float4v){0.f, 0.f, 0.f, 0.f};

    int mrow = m_base + ln;
    if (mrow >= M) mrow = M - 1;   // clamp loads; stores guarded

    const int KSTEPS = K / 32;
#pragma unroll
    for (int ks = 0; ks < KSTEPS; ++ks) {
        const int k0 = ks * 32 + q * 8;
        short8 afrag;
        if constexpr (A_IS_BF16) {
            const unsigned short* A = (const unsigned short*)Av;
            afrag = *reinterpret_cast<const short8*>(A + (size_t)mrow * K + k0);
        } else {
            const float* A = (const float*)Av;
            const float4v* p = reinterpret_cast<const float4v*>(A + (size_t)mrow * K + k0);
            float4v f0 = p[0], f1 = p[1];
            afrag[0] = (short)f2bf(f0[0]); afrag[1] = (short)f2bf(f0[1]);
            afrag[2] = (short)f2bf(f0[2]); afrag[3] = (short)f2bf(f0[3]);
            afrag[4] = (short)f2bf(f1[0]); afrag[5] = (short)f2bf(f1[1]);
            afrag[6] = (short)f2bf(f1[2]); afrag[7] = (short)f2bf(f1[3]);
        }
#pragma unroll
        for (int nt = 0; nt < 4; ++nt) {
            const short8 bfrag = *reinterpret_cast<const short8*>(
                B + (size_t)(n_base + nt * 16 + ln) * K + k0);
            acc[nt] = __builtin_amdgcn_mfma_f32_16x16x32_bf16(afrag, bfrag, acc[nt], 0, 0, 0);
        }
    }

#pragma unroll
    for (int nt = 0; nt < 4; ++nt) {
        const int n = n_base + nt * 16 + ln;
        const float bv = bias[n];
#pragma unroll
        for (int r = 0; r < 4; ++r) {
            const int m = m_base + q * 4 + r;
            if (m < M) {
                float v = acc[nt][r] + bv;
                if constexpr (RELU) v = v > 0.f ? v : 0.f;
                if constexpr (OUT_BF16)
                    ((unsigned short*)Cv)[(size_t)m * Ntot + n] = f2bf(v);
                else
                    ((float*)Cv)[(size_t)m * Ntot + n] = v;
            }
        }
    }
}

// ---------------------------------------------------------------------------
// CSR build
// ---------------------------------------------------------------------------
__global__ __launch_bounds__(256) void hist_kernel(
    const int* __restrict__ ei, int* __restrict__ deg_cnt, int E)
{
    int e = blockIdx.x * 256 + threadIdx.x;
    if (e < E) atomicAdd(&deg_cnt[ei[E + e]], 1);
}

__global__ __launch_bounds__(1024) void scan_kernel(
    const int* __restrict__ deg, int* __restrict__ rowptr,
    int* __restrict__ wp, int n)
{
    const int T = 1024;
    const int tid = threadIdx.x;
    const int per = (n + T - 1) / T;
    const int start = tid * per;
    const int end = min(start + per, n);
    int sum = 0;
    for (int i = start; i < end; ++i) sum += deg[i];

    const int lane = tid & 63, wv = tid >> 6;
    int v = sum;
#pragma unroll
    for (int off = 1; off < 64; off <<= 1) {
        int t = __shfl_up(v, off);
        if (lane >= off) v += t;
    }
    __shared__ int wsum[16];
    if (lane == 63) wsum[wv] = v;
    __syncthreads();
    if (wv == 0 && lane < 16) {
        int wvv = wsum[lane];
#pragma unroll
        for (int off = 1; off < 16; off <<= 1) {
            int t = __shfl_up(wvv, off);
            if (lane >= off) wvv += t;
        }
        wsum[lane] = wvv;
    }
    __syncthreads();
    const int waveoff = (wv == 0) ? 0 : wsum[wv - 1];
    int run = waveoff + v - sum;
    for (int i = start; i < end; ++i) {
        rowptr[i] = run; wp[i] = run;
        run += deg[i];
    }
    if (tid == T - 1) rowptr[n] = run;
}

__global__ __launch_bounds__(256) void fill_kernel(
    const int* __restrict__ ei, int* __restrict__ wp,
    int* __restrict__ adjsrc, int E)
{
    int e = blockIdx.x * 256 + threadIdx.x;
    if (e < E) {
        int dst = ei[E + e];
        int slot = atomicAdd(&wp[dst], 1);
        adjsrc[slot] = ei[e];
    }
}

// ---------------------------------------------------------------------------
// mom[n][k] = sum of eattr over in-edges of n (layer-independent, once/call)
// Edge-parallel, fully coalesced eattr stream; atomic chains ~deg(n)~16.
// ---------------------------------------------------------------------------
__global__ __launch_bounds__(256) void mom_scatter(
    const int* __restrict__ ei, const float* __restrict__ eattr,
    float* __restrict__ mom, int E)
{
    int t = blockIdx.x * 256 + threadIdx.x;
    int e = t >> 4, k = t & 15;
    if (e < E)
        atomicAdd(&mom[(size_t)ei[E + e] * 16 + k], eattr[(size_t)e * 16 + k]);
}

// ---------------------------------------------------------------------------
// Gather aggregation over bf16 h:
// ag[n] = bf16( h[n] + Σ_in h[src] + be*(deg+1) + We·mom[n] )
// One wave per node; lane holds channels 2*lane,2*lane+1 (uint = ushort2).
// ---------------------------------------------------------------------------
__global__ __launch_bounds__(256) void aggregate_kernel(
    const unsigned short* __restrict__ h, const int* __restrict__ adjsrc,
    const int* __restrict__ rowptr, const float* __restrict__ mom,
    const float* __restrict__ We, const float* __restrict__ be,
    unsigned short* __restrict__ ag, int N)
{
    const int lane = threadIdx.x & 63;
    const int gwave = (blockIdx.x * 256 + threadIdx.x) >> 6;
    const int nwaves = (gridDim.x * 256) >> 6;
    const int c0 = 2 * lane;

    float w0[16], w1[16];
#pragma unroll
    for (int k = 0; k < 16; ++k) {
        w0[k] = We[c0 * 16 + k];
        w1[k] = We[(c0 + 1) * 16 + k];
    }
    const float b0 = be[c0], b1 = be[c0 + 1];

    for (int n = gwave; n < N; n += nwaves) {
        const int s = rowptr[n], e = rowptr[n + 1];
        unsigned int self = *reinterpret_cast<const unsigned int*>(
            h + (size_t)n * 128 + c0);
        float ax = bflo(self), ay = bfhi(self);
        float mval = (lane < 16) ? mom[(size_t)n * 16 + lane] : 0.f;

        int p = s;
        for (; p + 8 <= e; p += 8) {
            int s0 = adjsrc[p], s1 = adjsrc[p+1], s2 = adjsrc[p+2], s3 = adjsrc[p+3];
            int s4 = adjsrc[p+4], s5 = adjsrc[p+5], s6 = adjsrc[p+6], s7 = adjsrc[p+7];
            unsigned int v0 = *reinterpret_cast<const unsigned int*>(h + (size_t)s0 * 128 + c0);
            unsigned int v1 = *reinterpret_cast<const unsigned int*>(h + (size_t)s1 * 128 + c0);
            unsigned int v2 = *reinterpret_cast<const unsigned int*>(h + (size_t)s2 * 128 + c0);
            unsigned int v3 = *reinterpret_cast<const unsigned int*>(h + (size_t)s3 * 128 + c0);
            unsigned int v4 = *reinterpret_cast<const unsigned int*>(h + (size_t)s4 * 128 + c0);
            unsigned int v5 = *reinterpret_cast<const unsigned int*>(h + (size_t)s5 * 128 + c0);
            unsigned int v6 = *reinterpret_cast<const unsigned int*>(h + (size_t)s6 * 128 + c0);
            unsigned int v7 = *reinterpret_cast<const unsigned int*>(h + (size_t)s7 * 128 + c0);
            ax += bflo(v0) + bflo(v1) + bflo(v2) + bflo(v3)
                + bflo(v4) + bflo(v5) + bflo(v6) + bflo(v7);
            ay += bfhi(v0) + bfhi(v1) + bfhi(v2) + bfhi(v3)
                + bfhi(v4) + bfhi(v5) + bfhi(v6) + bfhi(v7);
        }
        for (; p < e; ++p) {
            int sv = adjsrc[p];
            unsigned int v = *reinterpret_cast<const unsigned int*>(
                h + (size_t)sv * 128 + c0);
            ax += bflo(v); ay += bfhi(v);
        }

        const float degp1 = (float)(e - s + 1);
        float d0 = b0 * degp1, d1 = b1 * degp1;
#pragma unroll
        for (int k = 0; k < 16; ++k) {
            const float sk = __shfl(mval, k);
            d0 += w0[k] * sk; d1 += w1[k] * sk;
        }
        ax += d0; ay += d1;
        *reinterpret_cast<unsigned int*>(ag + (size_t)n * 128 + c0) = packbf(ax, ay);
    }
}

// ---------------------------------------------------------------------------
// BatchNorm stats, two-stage (no same-address atomic chains)
// ---------------------------------------------------------------------------
__global__ __launch_bounds__(256) void bn_stats1(
    const float* __restrict__ h2, float* __restrict__ partial, int N)
{
    const int c = threadIdx.x & 127;
    const int sub = threadIdx.x >> 7;
    float s = 0.f, s2 = 0.f;
    const int stride = gridDim.x * 2;
    for (int n = blockIdx.x * 2 + sub; n < N; n += stride) {
        float v = h2[(size_t)n * 128 + c];
        s += v; s2 += v * v;
    }
    __shared__ float ls[256], ls2[256];
    ls[threadIdx.x] = s; ls2[threadIdx.x] = s2;
    __syncthreads();
    if (threadIdx.x < 128) {
        partial[blockIdx.x * 256 + c]       = ls[threadIdx.x]  + ls[threadIdx.x + 128];
        partial[blockIdx.x * 256 + 128 + c] = ls2[threadIdx.x] + ls2[threadIdx.x + 128];
    }
}

__global__ __launch_bounds__(256) void bn_stats2(
    const float* __restrict__ partial, float* __restrict__ sums, int nblk)
{
    const int t = threadIdx.x;   // 0..255: [0,128) sum, [128,256) sumsq
    float a = 0.f;
    for (int b = 0; b < nblk; ++b) a += partial[b * 256 + t];
    sums[t] = a;
}

// ---------------------------------------------------------------------------
// BN apply + relu -> bf16 h
// ---------------------------------------------------------------------------
__global__ __launch_bounds__(256) void bn_apply_bf16(
    const float* __restrict__ h2, const float* __restrict__ sums,
    const float* __restrict__ gamma, const float* __restrict__ beta,
    unsigned short* __restrict__ h, int total4, float invN)
{
    int tid = blockIdx.x * 256 + threadIdx.x;
    int c4 = (tid * 4) & 127;
    float sc[4], sh[4];
#pragma unroll
    for (int j = 0; j < 4; ++j) {
        int c = c4 + j;
        float mu = sums[c] * invN;
        float var = sums[128 + c] * invN - mu * mu;
        float s = gamma[c] * rsqrtf(fmaxf(var, 0.f) + BN_EPS);
        sc[j] = s;
        sh[j] = beta[c] - mu * s;
    }
    int stride = gridDim.x * 256;
    for (int i = tid; i < total4; i += stride) {
        float4v v = reinterpret_cast<const float4v*>(h2)[i];
        float x0 = fmaxf(sc[0] * v[0] + sh[0], 0.f);
        float x1 = fmaxf(sc[1] * v[1] + sh[1], 0.f);
        float x2 = fmaxf(sc[2] * v[2] + sh[2], 0.f);
        float x3 = fmaxf(sc[3] * v[3] + sh[3], 0.f);
        uint2 o; o.x = packbf(x0, x1); o.y = packbf(x2, x3);
        reinterpret_cast<uint2*>(h)[i] = o;
    }
}

// ---------------------------------------------------------------------------
// Fused pool + final BN affine + head. batch sorted -> binary search segment.
// h_final = sc*h2 + sh (no relu on last layer); mean commutes with affine.
// ---------------------------------------------------------------------------
__global__ __launch_bounds__(256) void pool_head(
    const float* __restrict__ h2, const int* __restrict__ batch,
    const float* __restrict__ sums, const float* __restrict__ gamma,
    const float* __restrict__ beta, const float* __restrict__ Wp,
    const float* __restrict__ bp, float* __restrict__ out, int N, float invN)
{
    const int g = blockIdx.x;
    __shared__ int sb[2];
    if (threadIdx.x < 2) {
        int target = g + threadIdx.x;
        int lo = 0, hi = N;
        while (lo < hi) {
            int mid = (lo + hi) >> 1;
            if (batch[mid] < target) lo = mid + 1; else hi = mid;
        }
        sb[threadIdx.x] = lo;
    }
    __syncthreads();
    const int s = sb[0], e = sb[1];
    const int c = threadIdx.x & 127;
    const int sub = threadIdx.x >> 7;
    float acc = 0.f;
    for (int n = s + sub; n < e; n += 2) acc += h2[(size_t)n * 128 + c];
    __shared__ float red[256];
    red[threadIdx.x] = acc;
    __syncthreads();
    if (threadIdx.x < 128) {
        float m = (red[threadIdx.x] + red[threadIdx.x + 128]) /
                  fmaxf((float)(e - s), 1.f);
        float mu = sums[c] * invN;
        float var = sums[128 + c] * invN - mu * mu;
        float sc = gamma[c] * rsqrtf(fmaxf(var, 0.f) + BN_EPS);
        float sh = beta[c] - mu * sc;
        red[threadIdx.x] = (sc * m + sh) * Wp[c];
    }
    __syncthreads();
    for (int st = 64; st > 0; st >>= 1) {
        if (threadIdx.x < st) red[threadIdx.x] += red[threadIdx.x + st];
        __syncthreads();
    }
    if (threadIdx.x == 0) out[g] = red[0] + bp[0];
}

// ---------------------------------------------------------------------------
extern "C" void kernel_launch(void* const* d_in, const int* in_sizes, int n_in,
                              void* d_out, int out_size, void* d_ws, size_t ws_size,
                              hipStream_t stream)
{
    const float* x     = (const float*)d_in[0];
    const float* eattr = (const float*)d_in[1];
    const float* W0    = (const float*)d_in[2];
    const float* b0    = (const float*)d_in[3];
    const float* We    = (const float*)d_in[4];
    const float* be    = (const float*)d_in[5];
    const float* W1    = (const float*)d_in[6];
    const float* b1    = (const float*)d_in[7];
    const float* W2    = (const float*)d_in[8];
    const float* b2    = (const float*)d_in[9];
    const float* gamma = (const float*)d_in[10];
    const float* beta  = (const float*)d_in[11];
    const float* Wp    = (const float*)d_in[12];
    const float* bp    = (const float*)d_in[13];
    const int* ei    = (const int*)d_in[14];
    const int* batch = (const int*)d_in[15];

    const int N = in_sizes[0] / 32;   // 50000
    const int E = in_sizes[1] / 16;   // 800000

    char* ws = (char*)d_ws;
    size_t off = 0;
    auto alloc = [&](size_t bytes) { char* p = ws + off; off += (bytes + 255) & ~(size_t)255; return p; };
    // Region A (25.6MB): Y bf16 [N,256]; hb bf16 [N,128] aliases first half
    unsigned short* Y  = (unsigned short*)alloc((size_t)N * 256 * 2);
    unsigned short* hb = Y;
    // Region B (25.6MB): h2 f32 [N,128]; ag bf16 [N,128] aliases first half
    float* h2 = (float*)alloc((size_t)N * 128 * 4);
    unsigned short* ag = (unsigned short*)h2;
    float* partial = (float*)alloc(256 * 256 * 4);
    float* sums    = (float*)alloc(256 * 4);
    float* mom     = (float*)alloc((size_t)N * 16 * 4);
    unsigned short* W0bf = (unsigned short*)alloc(128 * 32 * 2);
    unsigned short* W1bf = (unsigned short*)alloc(3 * 256 * 128 * 2);
    unsigned short* W2bf = (unsigned short*)alloc(3 * 128 * 256 * 2);
    int* deg_cnt = (int*)alloc((size_t)N * 4);
    int* rowptr  = (int*)alloc(((size_t)N + 1) * 4);
    int* wp      = (int*)alloc((size_t)N * 4);
    int* adjsrc  = (int*)alloc((size_t)E * 4);

    const dim3 blk(256);
    const int mblocks = (N + 63) / 64;
    const int total4 = N * 32;
    const int eblocks = (E + 255) / 256;
    const float invN = 1.0f / (float)N;

    // --- CSR + edge-attr moments (once, reused by all layers) ---
    hipMemsetAsync(deg_cnt, 0, (size_t)N * 4, stream);
    hipMemsetAsync(mom, 0, (size_t)N * 16 * 4, stream);
    hist_kernel<<<dim3(eblocks), blk, 0, stream>>>(ei, deg_cnt, E);
    scan_kernel<<<dim3(1), dim3(1024), 0, stream>>>(deg_cnt, rowptr, wp, N);
    fill_kernel<<<dim3(eblocks), blk, 0, stream>>>(ei, wp, adjsrc, E);
    mom_scatter<<<dim3((E * 16 + 255) / 256), blk, 0, stream>>>(ei, eattr, mom, E);

    // --- weight pre-conversion ---
    conv_bf16<<<dim3(16), blk, 0, stream>>>(W0, W0bf, 128 * 32);
    conv_bf16<<<dim3(384), blk, 0, stream>>>(W1, W1bf, 3 * 256 * 128);
    conv_bf16<<<dim3(384), blk, 0, stream>>>(W2, W2bf, 3 * 128 * 256);

    // h = bf16(x @ W0^T + b0)
    gemm_bt<32, false, false, true><<<dim3(mblocks, 2), blk, 0, stream>>>(
        x, W0bf, b0, (void*)hb, N, 128);

    for (int l = 0; l < LAYERS; ++l) {
        aggregate_kernel<<<dim3(2048), blk, 0, stream>>>(
            hb, adjsrc, rowptr, mom, We + l * 128 * 16, be + l * 128, ag, N);
        // Y = bf16(relu(ag @ W1^T + b1))  [N,256]
        gemm_bt<128, true, true, true><<<dim3(mblocks, 4), blk, 0, stream>>>(
            ag, W1bf + l * 256 * 128, b1 + l * 256, (void*)Y, N, 256);
        // h2 = Y @ W2^T + b2  [N,128] f32   (overwrites ag region - ag dead)
        gemm_bt<256, true, false, false><<<dim3(mblocks, 2), blk, 0, stream>>>(
            Y, W2bf + l * 128 * 256, b2 + l * 128, (void*)h2, N, 128);
        bn_stats1<<<dim3(256), blk, 0, stream>>>(h2, partial, N);
        bn_stats2<<<dim3(1), blk, 0, stream>>>(partial, sums, 256);
        if (l < LAYERS - 1)
            bn_apply_bf16<<<dim3(1024), blk, 0, stream>>>(
                h2, sums, gamma + l * 128, beta + l * 128, hb, total4, invN);
    }

    // final layer: fold BN affine into pooling (linear, no relu)
    pool_head<<<dim3(NGRAPHS), blk, 0, stream>>>(
        h2, batch, sums, gamma + 2 * 128, beta + 2 * 128, Wp, bp,
        (float*)d_out, N, invN);
}

// Round 5
// 1030.407 us; speedup vs baseline: 1.9790x; 1.1029x over previous
//
#include <hip/hip_runtime.h>
#include <stdint.h>

#define EMB 128
#define LAYERS 3
#define NGRAPHS 64
#define BN_EPS 1e-5f

typedef short short8 __attribute__((ext_vector_type(8)));
typedef float float4v __attribute__((ext_vector_type(4)));

__device__ __forceinline__ unsigned short f2bf(float f) {
    union { float f; unsigned int i; } v; v.f = f;
    unsigned int x = v.i;
    unsigned int r = x + 0x7FFFu + ((x >> 16) & 1u);
    return (unsigned short)(r >> 16);
}
__device__ __forceinline__ float bflo(unsigned int u) {
    union { unsigned int i; float f; } v; v.i = u << 16; return v.f;
}
__device__ __forceinline__ float bfhi(unsigned int u) {
    union { unsigned int i; float f; } v; v.i = u & 0xffff0000u; return v.f;
}
__device__ __forceinline__ unsigned int packbf(float a, float b) {
    return (unsigned int)f2bf(a) | ((unsigned int)f2bf(b) << 16);
}

// f32 -> bf16 (RNE), three concatenated segments in one dispatch
__global__ __launch_bounds__(256) void conv_bf16_3(
    const float* __restrict__ a, unsigned short* __restrict__ oa, int na,
    const float* __restrict__ b, unsigned short* __restrict__ ob, int nb,
    const float* __restrict__ c, unsigned short* __restrict__ oc, int nc)
{
    int i = blockIdx.x * 256 + threadIdx.x;
    int stride = gridDim.x * 256;
    for (int t = i; t < na + nb + nc; t += stride) {
        if (t < na) oa[t] = f2bf(a[t]);
        else if (t < na + nb) ob[t - na] = f2bf(b[t - na]);
        else oc[t - na - nb] = f2bf(c[t - na - nb]);
    }
}

// ---------------------------------------------------------------------------
// GEMM: C[M,Ntot] = epilogue(A[M,K] @ B[Ntot,K]^T + bias)
// ---------------------------------------------------------------------------
template<int K, bool A_IS_BF16, bool RELU, bool OUT_BF16>
__global__ __launch_bounds__(256) void gemm_bt(
    const void* __restrict__ Av, const unsigned short* __restrict__ B,
    const float* __restrict__ bias, void* __restrict__ Cv,
    int M, int Ntot)
{
    const int wave = threadIdx.x >> 6;
    const int lane = threadIdx.x & 63;
    const int q    = lane >> 4;
    const int ln   = lane & 15;
    const int m_base = blockIdx.x * 64 + wave * 16;
    const int n_base = blockIdx.y * 64;

    float4v acc[4];
#pragma unroll
    for (int i = 0; i < 4; ++i) acc[i] = (float4v){0.f, 0.f, 0.f, 0.f};

    int mrow = m_base + ln;
    if (mrow >= M) mrow = M - 1;   // clamp loads; stores guarded

    const int KSTEPS = K / 32;
#pragma unroll
    for (int ks = 0; ks < KSTEPS; ++ks) {
        const int k0 = ks * 32 + q * 8;
        short8 afrag;
        if constexpr (A_IS_BF16) {
            const unsigned short* A = (const unsigned short*)Av;
            afrag = *reinterpret_cast<const short8*>(A + (size_t)mrow * K + k0);
        } else {
            const float* A = (const float*)Av;
            const float4v* p = reinterpret_cast<const float4v*>(A + (size_t)mrow * K + k0);
            float4v f0 = p[0], f1 = p[1];
            afrag[0] = (short)f2bf(f0[0]); afrag[1] = (short)f2bf(f0[1]);
            afrag[2] = (short)f2bf(f0[2]); afrag[3] = (short)f2bf(f0[3]);
            afrag[4] = (short)f2bf(f1[0]); afrag[5] = (short)f2bf(f1[1]);
            afrag[6] = (short)f2bf(f1[2]); afrag[7] = (short)f2bf(f1[3]);
        }
#pragma unroll
        for (int nt = 0; nt < 4; ++nt) {
            const short8 bfrag = *reinterpret_cast<const short8*>(
                B + (size_t)(n_base + nt * 16 + ln) * K + k0);
            acc[nt] = __builtin_amdgcn_mfma_f32_16x16x32_bf16(afrag, bfrag, acc[nt], 0, 0, 0);
        }
    }

#pragma unroll
    for (int nt = 0; nt < 4; ++nt) {
        const int n = n_base + nt * 16 + ln;
        const float bv = bias[n];
#pragma unroll
        for (int r = 0; r < 4; ++r) {
            const int m = m_base + q * 4 + r;
            if (m < M) {
                float v = acc[nt][r] + bv;
                if constexpr (RELU) v = v > 0.f ? v : 0.f;
                if constexpr (OUT_BF16)
                    ((unsigned short*)Cv)[(size_t)m * Ntot + n] = f2bf(v);
                else
                    ((float*)Cv)[(size_t)m * Ntot + n] = v;
            }
        }
    }
}

// ---------------------------------------------------------------------------
// CSR build: histogram, 3-phase parallel scan, fill
// ---------------------------------------------------------------------------
__global__ __launch_bounds__(256) void hist_kernel(
    const int* __restrict__ ei, int* __restrict__ deg_cnt, int E)
{
    int e = blockIdx.x * 256 + threadIdx.x;
    if (e < E) atomicAdd(&deg_cnt[ei[E + e]], 1);
}

// phase 1: per-block (256-elem) sums
__global__ __launch_bounds__(256) void scan_part(
    const int* __restrict__ deg, int* __restrict__ blocksum, int n)
{
    int i = blockIdx.x * 256 + threadIdx.x;
    int v = (i < n) ? deg[i] : 0;
    const int lane = threadIdx.x & 63;
#pragma unroll
    for (int off = 32; off > 0; off >>= 1) v += __shfl_down(v, off);
    __shared__ int ws[4];
    if (lane == 0) ws[threadIdx.x >> 6] = v;
    __syncthreads();
    if (threadIdx.x == 0)
        blocksum[blockIdx.x] = ws[0] + ws[1] + ws[2] + ws[3];
}

// phase 2: single block exclusive-scans nblk (<=256) block sums
__global__ __launch_bounds__(256) void scan_top(
    int* __restrict__ blocksum, int nblk)
{
    const int t = threadIdx.x;
    int v = (t < nblk) ? blocksum[t] : 0;
    const int lane = t & 63, wv = t >> 6;
    int iv = v;
#pragma unroll
    for (int off = 1; off < 64; off <<= 1) {
        int u = __shfl_up(iv, off);
        if (lane >= off) iv += u;
    }
    __shared__ int ws[4];
    if (lane == 63) ws[wv] = iv;
    __syncthreads();
    int woff = 0;
    for (int j = 0; j < wv; ++j) woff += ws[j];
    if (t < nblk) blocksum[t] = woff + iv - v;   // exclusive prefix
}

// phase 3: intra-block exclusive scan + block offset -> rowptr, wp
__global__ __launch_bounds__(256) void scan_emit(
    const int* __restrict__ deg, const int* __restrict__ blockoff,
    int* __restrict__ rowptr, int* __restrict__ wp, int n)
{
    int i = blockIdx.x * 256 + threadIdx.x;
    int v = (i < n) ? deg[i] : 0;
    const int lane = threadIdx.x & 63, wv = threadIdx.x >> 6;
    int iv = v;
#pragma unroll
    for (int off = 1; off < 64; off <<= 1) {
        int u = __shfl_up(iv, off);
        if (lane >= off) iv += u;
    }
    __shared__ int ws[4];
    if (lane == 63) ws[wv] = iv;
    __syncthreads();
    int woff = blockoff[blockIdx.x];
    for (int j = 0; j < wv; ++j) woff += ws[j];
    int ex = woff + iv - v;
    if (i < n) { rowptr[i] = ex; wp[i] = ex; }
    if (i == n - 1) rowptr[n] = ex + v;
}

__global__ __launch_bounds__(256) void fill_kernel(
    const int* __restrict__ ei, int* __restrict__ wp,
    int* __restrict__ adjsrc, int E)
{
    int e = blockIdx.x * 256 + threadIdx.x;
    if (e < E) {
        int dst = ei[E + e];
        int slot = atomicAdd(&wp[dst], 1);
        adjsrc[slot] = ei[e];
    }
}

// ---------------------------------------------------------------------------
// mom[n][k] = sum of eattr over in-edges of n (layer-independent, once/call)
// ---------------------------------------------------------------------------
__global__ __launch_bounds__(256) void mom_scatter(
    const int* __restrict__ ei, const float* __restrict__ eattr,
    float* __restrict__ mom, int E)
{
    int t = blockIdx.x * 256 + threadIdx.x;
    int e = t >> 4, k = t & 15;
    if (e < E)
        atomicAdd(&mom[(size_t)ei[E + e] * 16 + k], eattr[(size_t)e * 16 + k]);
}

// ---------------------------------------------------------------------------
// Gather aggregation over bf16 h:
// ag[n] = bf16( h[n] + Σ_in h[src] + be*(deg+1) + We·mom[n] )
// ---------------------------------------------------------------------------
__global__ __launch_bounds__(256) void aggregate_kernel(
    const unsigned short* __restrict__ h, const int* __restrict__ adjsrc,
    const int* __restrict__ rowptr, const float* __restrict__ mom,
    const float* __restrict__ We, const float* __restrict__ be,
    unsigned short* __restrict__ ag, int N)
{
    const int lane = threadIdx.x & 63;
    const int gwave = (blockIdx.x * 256 + threadIdx.x) >> 6;
    const int nwaves = (gridDim.x * 256) >> 6;
    const int c0 = 2 * lane;

    float w0[16], w1[16];
#pragma unroll
    for (int k = 0; k < 16; ++k) {
        w0[k] = We[c0 * 16 + k];
        w1[k] = We[(c0 + 1) * 16 + k];
    }
    const float b0 = be[c0], b1 = be[c0 + 1];

    for (int n = gwave; n < N; n += nwaves) {
        const int s = rowptr[n], e = rowptr[n + 1];
        unsigned int self = *reinterpret_cast<const unsigned int*>(
            h + (size_t)n * 128 + c0);
        float ax = bflo(self), ay = bfhi(self);
        float mval = (lane < 16) ? mom[(size_t)n * 16 + lane] : 0.f;

        int p = s;
        for (; p + 8 <= e; p += 8) {
            int s0 = adjsrc[p], s1 = adjsrc[p+1], s2 = adjsrc[p+2], s3 = adjsrc[p+3];
            int s4 = adjsrc[p+4], s5 = adjsrc[p+5], s6 = adjsrc[p+6], s7 = adjsrc[p+7];
            unsigned int v0 = *reinterpret_cast<const unsigned int*>(h + (size_t)s0 * 128 + c0);
            unsigned int v1 = *reinterpret_cast<const unsigned int*>(h + (size_t)s1 * 128 + c0);
            unsigned int v2 = *reinterpret_cast<const unsigned int*>(h + (size_t)s2 * 128 + c0);
            unsigned int v3 = *reinterpret_cast<const unsigned int*>(h + (size_t)s3 * 128 + c0);
            unsigned int v4 = *reinterpret_cast<const unsigned int*>(h + (size_t)s4 * 128 + c0);
            unsigned int v5 = *reinterpret_cast<const unsigned int*>(h + (size_t)s5 * 128 + c0);
            unsigned int v6 = *reinterpret_cast<const unsigned int*>(h + (size_t)s6 * 128 + c0);
            unsigned int v7 = *reinterpret_cast<const unsigned int*>(h + (size_t)s7 * 128 + c0);
            ax += bflo(v0) + bflo(v1) + bflo(v2) + bflo(v3)
                + bflo(v4) + bflo(v5) + bflo(v6) + bflo(v7);
            ay += bfhi(v0) + bfhi(v1) + bfhi(v2) + bfhi(v3)
                + bfhi(v4) + bfhi(v5) + bfhi(v6) + bfhi(v7);
        }
        for (; p < e; ++p) {
            int sv = adjsrc[p];
            unsigned int v = *reinterpret_cast<const unsigned int*>(
                h + (size_t)sv * 128 + c0);
            ax += bflo(v); ay += bfhi(v);
        }

        const float degp1 = (float)(e - s + 1);
        float d0 = b0 * degp1, d1 = b1 * degp1;
#pragma unroll
        for (int k = 0; k < 16; ++k) {
            const float sk = __shfl(mval, k);
            d0 += w0[k] * sk; d1 += w1[k] * sk;
        }
        ax += d0; ay += d1;
        *reinterpret_cast<unsigned int*>(ag + (size_t)n * 128 + c0) = packbf(ax, ay);
    }
}

// ---------------------------------------------------------------------------
// BatchNorm stats, two-stage
// ---------------------------------------------------------------------------
__global__ __launch_bounds__(256) void bn_stats1(
    const float* __restrict__ h2, float* __restrict__ partial, int N)
{
    const int c = threadIdx.x & 127;
    const int sub = threadIdx.x >> 7;
    float s = 0.f, s2 = 0.f;
    const int stride = gridDim.x * 2;
    for (int n = blockIdx.x * 2 + sub; n < N; n += stride) {
        float v = h2[(size_t)n * 128 + c];
        s += v; s2 += v * v;
    }
    __shared__ float ls[256], ls2[256];
    ls[threadIdx.x] = s; ls2[threadIdx.x] = s2;
    __syncthreads();
    if (threadIdx.x < 128) {
        partial[blockIdx.x * 256 + c]       = ls[threadIdx.x]  + ls[threadIdx.x + 128];
        partial[blockIdx.x * 256 + 128 + c] = ls2[threadIdx.x] + ls2[threadIdx.x + 128];
    }
}

__global__ __launch_bounds__(256) void bn_stats2(
    const float* __restrict__ partial, float* __restrict__ sums, int nblk)
{
    const int t = threadIdx.x;
    float a = 0.f;
    for (int b = 0; b < nblk; ++b) a += partial[b * 256 + t];
    sums[t] = a;
}

// ---------------------------------------------------------------------------
// BN apply + relu -> bf16 h
// ---------------------------------------------------------------------------
__global__ __launch_bounds__(256) void bn_apply_bf16(
    const float* __restrict__ h2, const float* __restrict__ sums,
    const float* __restrict__ gamma, const float* __restrict__ beta,
    unsigned short* __restrict__ h, int total4, float invN)
{
    int tid = blockIdx.x * 256 + threadIdx.x;
    int c4 = (tid * 4) & 127;
    float sc[4], sh[4];
#pragma unroll
    for (int j = 0; j < 4; ++j) {
        int c = c4 + j;
        float mu = sums[c] * invN;
        float var = sums[128 + c] * invN - mu * mu;
        float s = gamma[c] * rsqrtf(fmaxf(var, 0.f) + BN_EPS);
        sc[j] = s;
        sh[j] = beta[c] - mu * s;
    }
    int stride = gridDim.x * 256;
    for (int i = tid; i < total4; i += stride) {
        float4v v = reinterpret_cast<const float4v*>(h2)[i];
        float x0 = fmaxf(sc[0] * v[0] + sh[0], 0.f);
        float x1 = fmaxf(sc[1] * v[1] + sh[1], 0.f);
        float x2 = fmaxf(sc[2] * v[2] + sh[2], 0.f);
        float x3 = fmaxf(sc[3] * v[3] + sh[3], 0.f);
        uint2 o; o.x = packbf(x0, x1); o.y = packbf(x2, x3);
        reinterpret_cast<uint2*>(h)[i] = o;
    }
}

// ---------------------------------------------------------------------------
// Fused pool + final BN affine + head
// ---------------------------------------------------------------------------
__global__ __launch_bounds__(256) void pool_head(
    const float* __restrict__ h2, const int* __restrict__ batch,
    const float* __restrict__ sums, const float* __restrict__ gamma,
    const float* __restrict__ beta, const float* __restrict__ Wp,
    const float* __restrict__ bp, float* __restrict__ out, int N, float invN)
{
    const int g = blockIdx.x;
    __shared__ int sb[2];
    if (threadIdx.x < 2) {
        int target = g + threadIdx.x;
        int lo = 0, hi = N;
        while (lo < hi) {
            int mid = (lo + hi) >> 1;
            if (batch[mid] < target) lo = mid + 1; else hi = mid;
        }
        sb[threadIdx.x] = lo;
    }
    __syncthreads();
    const int s = sb[0], e = sb[1];
    const int c = threadIdx.x & 127;
    const int sub = threadIdx.x >> 7;
    float acc = 0.f;
    for (int n = s + sub; n < e; n += 2) acc += h2[(size_t)n * 128 + c];
    __shared__ float red[256];
    red[threadIdx.x] = acc;
    __syncthreads();
    if (threadIdx.x < 128) {
        float m = (red[threadIdx.x] + red[threadIdx.x + 128]) /
                  fmaxf((float)(e - s), 1.f);
        float mu = sums[c] * invN;
        float var = sums[128 + c] * invN - mu * mu;
        float sc = gamma[c] * rsqrtf(fmaxf(var, 0.f) + BN_EPS);
        float sh = beta[c] - mu * sc;
        red[threadIdx.x] = (sc * m + sh) * Wp[c];
    }
    __syncthreads();
    for (int st = 64; st > 0; st >>= 1) {
        if (threadIdx.x < st) red[threadIdx.x] += red[threadIdx.x + st];
        __syncthreads();
    }
    if (threadIdx.x == 0) out[g] = red[0] + bp[0];
}

// ---------------------------------------------------------------------------
extern "C" void kernel_launch(void* const* d_in, const int* in_sizes, int n_in,
                              void* d_out, int out_size, void* d_ws, size_t ws_size,
                              hipStream_t stream)
{
    const float* x     = (const float*)d_in[0];
    const float* eattr = (const float*)d_in[1];
    const float* W0    = (const float*)d_in[2];
    const float* b0    = (const float*)d_in[3];
    const float* We    = (const float*)d_in[4];
    const float* be    = (const float*)d_in[5];
    const float* W1    = (const float*)d_in[6];
    const float* b1    = (const float*)d_in[7];
    const float* W2    = (const float*)d_in[8];
    const float* b2    = (const float*)d_in[9];
    const float* gamma = (const float*)d_in[10];
    const float* beta  = (const float*)d_in[11];
    const float* Wp    = (const float*)d_in[12];
    const float* bp    = (const float*)d_in[13];
    const int* ei    = (const int*)d_in[14];
    const int* batch = (const int*)d_in[15];

    const int N = in_sizes[0] / 32;   // 50000
    const int E = in_sizes[1] / 16;   // 800000

    char* ws = (char*)d_ws;
    size_t off = 0;
    auto alloc = [&](size_t bytes) { char* p = ws + off; off += (bytes + 255) & ~(size_t)255; return p; };
    unsigned short* Y  = (unsigned short*)alloc((size_t)N * 256 * 2);
    unsigned short* hb = Y;
    float* h2 = (float*)alloc((size_t)N * 128 * 4);
    unsigned short* ag = (unsigned short*)h2;
    float* partial = (float*)alloc(256 * 256 * 4);
    float* sums    = (float*)alloc(256 * 4);
    float* mom     = (float*)alloc((size_t)N * 16 * 4);
    unsigned short* W0bf = (unsigned short*)alloc(128 * 32 * 2);
    unsigned short* W1bf = (unsigned short*)alloc(3 * 256 * 128 * 2);
    unsigned short* W2bf = (unsigned short*)alloc(3 * 128 * 256 * 2);
    int* deg_cnt  = (int*)alloc((size_t)N * 4);
    int* rowptr   = (int*)alloc(((size_t)N + 1) * 4);
    int* wp       = (int*)alloc((size_t)N * 4);
    int* blocksum = (int*)alloc(256 * 4);
    int* adjsrc   = (int*)alloc((size_t)E * 4);

    const dim3 blk(256);
    const int mblocks = (N + 63) / 64;
    const int total4 = N * 32;
    const int eblocks = (E + 255) / 256;
    const int sblocks = (N + 255) / 256;   // 196 <= 256 (single-level top scan ok)
    const float invN = 1.0f / (float)N;

    // --- CSR + edge-attr moments (once, reused by all layers) ---
    hipMemsetAsync(deg_cnt, 0, (size_t)N * 4, stream);
    hipMemsetAsync(mom, 0, (size_t)N * 16 * 4, stream);
    hist_kernel<<<dim3(eblocks), blk, 0, stream>>>(ei, deg_cnt, E);
    scan_part<<<dim3(sblocks), blk, 0, stream>>>(deg_cnt, blocksum, N);
    scan_top<<<dim3(1), blk, 0, stream>>>(blocksum, sblocks);
    scan_emit<<<dim3(sblocks), blk, 0, stream>>>(deg_cnt, blocksum, rowptr, wp, N);
    fill_kernel<<<dim3(eblocks), blk, 0, stream>>>(ei, wp, adjsrc, E);
    mom_scatter<<<dim3((E * 16 + 255) / 256), blk, 0, stream>>>(ei, eattr, mom, E);

    // --- weight pre-conversion (one dispatch) ---
    conv_bf16_3<<<dim3(384), blk, 0, stream>>>(
        W0, W0bf, 128 * 32, W1, W1bf, 3 * 256 * 128, W2, W2bf, 3 * 128 * 256);

    // h = bf16(x @ W0^T + b0)
    gemm_bt<32, false, false, true><<<dim3(mblocks, 2), blk, 0, stream>>>(
        x, W0bf, b0, (void*)hb, N, 128);

    for (int l = 0; l < LAYERS; ++l) {
        aggregate_kernel<<<dim3(2048), blk, 0, stream>>>(
            hb, adjsrc, rowptr, mom, We + l * 128 * 16, be + l * 128, ag, N);
        gemm_bt<128, true, true, true><<<dim3(mblocks, 4), blk, 0, stream>>>(
            ag, W1bf + l * 256 * 128, b1 + l * 256, (void*)Y, N, 256);
        gemm_bt<256, true, false, false><<<dim3(mblocks, 2), blk, 0, stream>>>(
            Y, W2bf + l * 128 * 256, b2 + l * 128, (void*)h2, N, 128);
        bn_stats1<<<dim3(256), blk, 0, stream>>>(h2, partial, N);
        bn_stats2<<<dim3(1), blk, 0, stream>>>(partial, sums, 256);
        if (l < LAYERS - 1)
            bn_apply_bf16<<<dim3(1024), blk, 0, stream>>>(
                h2, sums, gamma + l * 128, beta + l * 128, hb, total4, invN);
    }

    pool_head<<<dim3(NGRAPHS), blk, 0, stream>>>(
        h2, batch, sums, gamma + 2 * 128, beta + 2 * 128, Wp, bp,
        (float*)d_out, N, invN);
}

// Round 6
// 960.291 us; speedup vs baseline: 2.1235x; 1.0730x over previous
//
#include <hip/hip_runtime.h>
#include <stdint.h>

#define EMB 128
#define LAYERS 3
#define NGRAPHS 64
#define BN_EPS 1e-5f

typedef short short8 __attribute__((ext_vector_type(8)));
typedef float float4v __attribute__((ext_vector_type(4)));

__device__ __forceinline__ unsigned short f2bf(float f) {
    union { float f; unsigned int i; } v; v.f = f;
    unsigned int x = v.i;
    unsigned int r = x + 0x7FFFu + ((x >> 16) & 1u);
    return (unsigned short)(r >> 16);
}
__device__ __forceinline__ float bflo(unsigned int u) {
    union { unsigned int i; float f; } v; v.i = u << 16; return v.f;
}
__device__ __forceinline__ float bfhi(unsigned int u) {
    union { unsigned int i; float f; } v; v.i = u & 0xffff0000u; return v.f;
}
__device__ __forceinline__ unsigned int packbf(float a, float b) {
    return (unsigned int)f2bf(a) | ((unsigned int)f2bf(b) << 16);
}

// f32 -> bf16 (RNE), three concatenated segments in one dispatch
__global__ __launch_bounds__(256) void conv_bf16_3(
    const float* __restrict__ a, unsigned short* __restrict__ oa, int na,
    const float* __restrict__ b, unsigned short* __restrict__ ob, int nb,
    const float* __restrict__ c, unsigned short* __restrict__ oc, int nc)
{
    int i = blockIdx.x * 256 + threadIdx.x;
    int stride = gridDim.x * 256;
    for (int t = i; t < na + nb + nc; t += stride) {
        if (t < na) oa[t] = f2bf(a[t]);
        else if (t < na + nb) ob[t - na] = f2bf(b[t - na]);
        else oc[t - na - nb] = f2bf(c[t - na - nb]);
    }
}

// ---------------------------------------------------------------------------
// GEMM: C[M,Ntot] = epilogue(A[M,K] @ B[Ntot,K]^T + bias)
// ---------------------------------------------------------------------------
template<int K, bool A_IS_BF16, bool RELU, bool OUT_BF16>
__global__ __launch_bounds__(256) void gemm_bt(
    const void* __restrict__ Av, const unsigned short* __restrict__ B,
    const float* __restrict__ bias, void* __restrict__ Cv,
    int M, int Ntot)
{
    const int wave = threadIdx.x >> 6;
    const int lane = threadIdx.x & 63;
    const int q    = lane >> 4;
    const int ln   = lane & 15;
    const int m_base = blockIdx.x * 64 + wave * 16;
    const int n_base = blockIdx.y * 64;

    float4v acc[4];
#pragma unroll
    for (int i = 0; i < 4; ++i) acc[i] = (float4v){0.f, 0.f, 0.f, 0.f};

    int mrow = m_base + ln;
    if (mrow >= M) mrow = M - 1;   // clamp loads; stores guarded

    const int KSTEPS = K / 32;
#pragma unroll
    for (int ks = 0; ks < KSTEPS; ++ks) {
        const int k0 = ks * 32 + q * 8;
        short8 afrag;
        if constexpr (A_IS_BF16) {
            const unsigned short* A = (const unsigned short*)Av;
            afrag = *reinterpret_cast<const short8*>(A + (size_t)mrow * K + k0);
        } else {
            const float* A = (const float*)Av;
            const float4v* p = reinterpret_cast<const float4v*>(A + (size_t)mrow * K + k0);
            float4v f0 = p[0], f1 = p[1];
            afrag[0] = (short)f2bf(f0[0]); afrag[1] = (short)f2bf(f0[1]);
            afrag[2] = (short)f2bf(f0[2]); afrag[3] = (short)f2bf(f0[3]);
            afrag[4] = (short)f2bf(f1[0]); afrag[5] = (short)f2bf(f1[1]);
            afrag[6] = (short)f2bf(f1[2]); afrag[7] = (short)f2bf(f1[3]);
        }
#pragma unroll
        for (int nt = 0; nt < 4; ++nt) {
            const short8 bfrag = *reinterpret_cast<const short8*>(
                B + (size_t)(n_base + nt * 16 + ln) * K + k0);
            acc[nt] = __builtin_amdgcn_mfma_f32_16x16x32_bf16(afrag, bfrag, acc[nt], 0, 0, 0);
        }
    }

#pragma unroll
    for (int nt = 0; nt < 4; ++nt) {
        const int n = n_base + nt * 16 + ln;
        const float bv = bias[n];
#pragma unroll
        for (int r = 0; r < 4; ++r) {
            const int m = m_base + q * 4 + r;
            if (m < M) {
                float v = acc[nt][r] + bv;
                if constexpr (RELU) v = v > 0.f ? v : 0.f;
                if constexpr (OUT_BF16)
                    ((unsigned short*)Cv)[(size_t)m * Ntot + n] = f2bf(v);
                else
                    ((float*)Cv)[(size_t)m * Ntot + n] = v;
            }
        }
    }
}

// ---------------------------------------------------------------------------
// CSR build: histogram, 3-phase parallel scan, fill
// ---------------------------------------------------------------------------
__global__ __launch_bounds__(256) void hist_kernel(
    const int* __restrict__ ei, int* __restrict__ deg_cnt, int E)
{
    int e = blockIdx.x * 256 + threadIdx.x;
    if (e < E) atomicAdd(&deg_cnt[ei[E + e]], 1);
}

__global__ __launch_bounds__(256) void scan_part(
    const int* __restrict__ deg, int* __restrict__ blocksum, int n)
{
    int i = blockIdx.x * 256 + threadIdx.x;
    int v = (i < n) ? deg[i] : 0;
    const int lane = threadIdx.x & 63;
#pragma unroll
    for (int off = 32; off > 0; off >>= 1) v += __shfl_down(v, off);
    __shared__ int ws[4];
    if (lane == 0) ws[threadIdx.x >> 6] = v;
    __syncthreads();
    if (threadIdx.x == 0)
        blocksum[blockIdx.x] = ws[0] + ws[1] + ws[2] + ws[3];
}

__global__ __launch_bounds__(256) void scan_top(
    int* __restrict__ blocksum, int nblk)
{
    const int t = threadIdx.x;
    int v = (t < nblk) ? blocksum[t] : 0;
    const int lane = t & 63, wv = t >> 6;
    int iv = v;
#pragma unroll
    for (int off = 1; off < 64; off <<= 1) {
        int u = __shfl_up(iv, off);
        if (lane >= off) iv += u;
    }
    __shared__ int ws[4];
    if (lane == 63) ws[wv] = iv;
    __syncthreads();
    int woff = 0;
    for (int j = 0; j < wv; ++j) woff += ws[j];
    if (t < nblk) blocksum[t] = woff + iv - v;   // exclusive prefix
}

__global__ __launch_bounds__(256) void scan_emit(
    const int* __restrict__ deg, const int* __restrict__ blockoff,
    int* __restrict__ rowptr, int* __restrict__ wp, int n)
{
    int i = blockIdx.x * 256 + threadIdx.x;
    int v = (i < n) ? deg[i] : 0;
    const int lane = threadIdx.x & 63, wv = threadIdx.x >> 6;
    int iv = v;
#pragma unroll
    for (int off = 1; off < 64; off <<= 1) {
        int u = __shfl_up(iv, off);
        if (lane >= off) iv += u;
    }
    __shared__ int ws[4];
    if (lane == 63) ws[wv] = iv;
    __syncthreads();
    int woff = blockoff[blockIdx.x];
    for (int j = 0; j < wv; ++j) woff += ws[j];
    int ex = woff + iv - v;
    if (i < n) { rowptr[i] = ex; wp[i] = ex; }
    if (i == n - 1) rowptr[n] = ex + v;
}

__global__ __launch_bounds__(256) void fill_kernel(
    const int* __restrict__ ei, int* __restrict__ wp,
    int* __restrict__ adjsrc, int E)
{
    int e = blockIdx.x * 256 + threadIdx.x;
    if (e < E) {
        int dst = ei[E + e];
        int slot = atomicAdd(&wp[dst], 1);
        adjsrc[slot] = ei[e];
    }
}

// ---------------------------------------------------------------------------
// mom[n][k] = sum of eattr over in-edges of n (layer-independent, once/call)
// ---------------------------------------------------------------------------
__global__ __launch_bounds__(256) void mom_scatter(
    const int* __restrict__ ei, const float* __restrict__ eattr,
    float* __restrict__ mom, int E)
{
    int t = blockIdx.x * 256 + threadIdx.x;
    int e = t >> 4, k = t & 15;
    if (e < E)
        atomicAdd(&mom[(size_t)ei[E + e] * 16 + k], eattr[(size_t)e * 16 + k]);
}

// ---------------------------------------------------------------------------
// Gather aggregation over bf16 h:
// ag[n] = bf16( h[n] + Σ_in h[src] + be*(deg+1) + We·mom[n] )
// ---------------------------------------------------------------------------
__global__ __launch_bounds__(256) void aggregate_kernel(
    const unsigned short* __restrict__ h, const int* __restrict__ adjsrc,
    const int* __restrict__ rowptr, const float* __restrict__ mom,
    const float* __restrict__ We, const float* __restrict__ be,
    unsigned short* __restrict__ ag, int N)
{
    const int lane = threadIdx.x & 63;
    const int gwave = (blockIdx.x * 256 + threadIdx.x) >> 6;
    const int nwaves = (gridDim.x * 256) >> 6;
    const int c0 = 2 * lane;

    float w0[16], w1[16];
#pragma unroll
    for (int k = 0; k < 16; ++k) {
        w0[k] = We[c0 * 16 + k];
        w1[k] = We[(c0 + 1) * 16 + k];
    }
    const float b0 = be[c0], b1 = be[c0 + 1];

    for (int n = gwave; n < N; n += nwaves) {
        const int s = rowptr[n], e = rowptr[n + 1];
        unsigned int self = *reinterpret_cast<const unsigned int*>(
            h + (size_t)n * 128 + c0);
        float ax = bflo(self), ay = bfhi(self);
        float mval = (lane < 16) ? mom[(size_t)n * 16 + lane] : 0.f;

        int p = s;
        for (; p + 8 <= e; p += 8) {
            int s0 = adjsrc[p], s1 = adjsrc[p+1], s2 = adjsrc[p+2], s3 = adjsrc[p+3];
            int s4 = adjsrc[p+4], s5 = adjsrc[p+5], s6 = adjsrc[p+6], s7 = adjsrc[p+7];
            unsigned int v0 = *reinterpret_cast<const unsigned int*>(h + (size_t)s0 * 128 + c0);
            unsigned int v1 = *reinterpret_cast<const unsigned int*>(h + (size_t)s1 * 128 + c0);
            unsigned int v2 = *reinterpret_cast<const unsigned int*>(h + (size_t)s2 * 128 + c0);
            unsigned int v3 = *reinterpret_cast<const unsigned int*>(h + (size_t)s3 * 128 + c0);
            unsigned int v4 = *reinterpret_cast<const unsigned int*>(h + (size_t)s4 * 128 + c0);
            unsigned int v5 = *reinterpret_cast<const unsigned int*>(h + (size_t)s5 * 128 + c0);
            unsigned int v6 = *reinterpret_cast<const unsigned int*>(h + (size_t)s6 * 128 + c0);
            unsigned int v7 = *reinterpret_cast<const unsigned int*>(h + (size_t)s7 * 128 + c0);
            ax += bflo(v0) + bflo(v1) + bflo(v2) + bflo(v3)
                + bflo(v4) + bflo(v5) + bflo(v6) + bflo(v7);
            ay += bfhi(v0) + bfhi(v1) + bfhi(v2) + bfhi(v3)
                + bfhi(v4) + bfhi(v5) + bfhi(v6) + bfhi(v7);
        }
        for (; p < e; ++p) {
            int sv = adjsrc[p];
            unsigned int v = *reinterpret_cast<const unsigned int*>(
                h + (size_t)sv * 128 + c0);
            ax += bflo(v); ay += bfhi(v);
        }

        const float degp1 = (float)(e - s + 1);
        float d0 = b0 * degp1, d1 = b1 * degp1;
#pragma unroll
        for (int k = 0; k < 16; ++k) {
            const float sk = __shfl(mval, k);
            d0 += w0[k] * sk; d1 += w1[k] * sk;
        }
        ax += d0; ay += d1;
        *reinterpret_cast<unsigned int*>(ag + (size_t)n * 128 + c0) = packbf(ax, ay);
    }
}

// ---------------------------------------------------------------------------
// BatchNorm stats, two-stage
// ---------------------------------------------------------------------------
__global__ __launch_bounds__(256) void bn_stats1(
    const float* __restrict__ h2, float* __restrict__ partial, int N)
{
    const int c = threadIdx.x & 127;
    const int sub = threadIdx.x >> 7;
    float s = 0.f, s2 = 0.f;
    const int stride = gridDim.x * 2;
    for (int n = blockIdx.x * 2 + sub; n < N; n += stride) {
        float v = h2[(size_t)n * 128 + c];
        s += v; s2 += v * v;
    }
    __shared__ float ls[256], ls2[256];
    ls[threadIdx.x] = s; ls2[threadIdx.x] = s2;
    __syncthreads();
    if (threadIdx.x < 128) {
        partial[blockIdx.x * 256 + c]       = ls[threadIdx.x]  + ls[threadIdx.x + 128];
        partial[blockIdx.x * 256 + 128 + c] = ls2[threadIdx.x] + ls2[threadIdx.x + 128];
    }
}

__global__ __launch_bounds__(256) void bn_stats2(
    const float* __restrict__ partial, float* __restrict__ sums, int nblk)
{
    const int t = threadIdx.x;
    float a = 0.f;
    for (int b = 0; b < nblk; ++b) a += partial[b * 256 + t];
    sums[t] = a;
}

// ---------------------------------------------------------------------------
// BN apply + relu -> bf16 h
// ---------------------------------------------------------------------------
__global__ __launch_bounds__(256) void bn_apply_bf16(
    const float* __restrict__ h2, const float* __restrict__ sums,
    const float* __restrict__ gamma, const float* __restrict__ beta,
    unsigned short* __restrict__ h, int total4, float invN)
{
    int tid = blockIdx.x * 256 + threadIdx.x;
    int c4 = (tid * 4) & 127;
    float sc[4], sh[4];
#pragma unroll
    for (int j = 0; j < 4; ++j) {
        int c = c4 + j;
        float mu = sums[c] * invN;
        float var = sums[128 + c] * invN - mu * mu;
        float s = gamma[c] * rsqrtf(fmaxf(var, 0.f) + BN_EPS);
        sc[j] = s;
        sh[j] = beta[c] - mu * s;
    }
    int stride = gridDim.x * 256;
    for (int i = tid; i < total4; i += stride) {
        float4v v = reinterpret_cast<const float4v*>(h2)[i];
        float x0 = fmaxf(sc[0] * v[0] + sh[0], 0.f);
        float x1 = fmaxf(sc[1] * v[1] + sh[1], 0.f);
        float x2 = fmaxf(sc[2] * v[2] + sh[2], 0.f);
        float x3 = fmaxf(sc[3] * v[3] + sh[3], 0.f);
        uint2 o; o.x = packbf(x0, x1); o.y = packbf(x2, x3);
        reinterpret_cast<uint2*>(h)[i] = o;
    }
}

// ---------------------------------------------------------------------------
// Pool stage 1: segmented sum over sorted batch keys. Each block owns a
// contiguous node slice; per-thread running accumulator, flushed to
// pooled[g][c] at graph boundaries (wave-uniform branch, few atomics).
// ---------------------------------------------------------------------------
__global__ __launch_bounds__(256) void pool_part(
    const float* __restrict__ h2, const int* __restrict__ batch,
    float* __restrict__ pooled, int N)
{
    const int per = (N + gridDim.x - 1) / gridDim.x;
    const int start = blockIdx.x * per;
    const int end = min(start + per, N);
    if (start >= end) return;
    const int c = threadIdx.x & 127;
    const int sub = threadIdx.x >> 7;
    int g_cur = batch[start];
    float acc = 0.f;
    for (int n = start + sub; n < end; n += 2) {
        int g = batch[n];
        if (g != g_cur) {
            if (acc != 0.f) atomicAdd(&pooled[(size_t)g_cur * 128 + c], acc);
            acc = 0.f; g_cur = g;
        }
        acc += h2[(size_t)n * 128 + c];
    }
    if (acc != 0.f) atomicAdd(&pooled[(size_t)g_cur * 128 + c], acc);
}

// ---------------------------------------------------------------------------
// Pool stage 2: mean + final BN affine (folded) + head dot. 64 blocks.
// ---------------------------------------------------------------------------
__global__ __launch_bounds__(128) void head_final(
    const float* __restrict__ pooled, const int* __restrict__ batch,
    const float* __restrict__ sums, const float* __restrict__ gamma,
    const float* __restrict__ beta, const float* __restrict__ Wp,
    const float* __restrict__ bp, float* __restrict__ out, int N, float invN)
{
    const int g = blockIdx.x;
    __shared__ int sb[2];
    if (threadIdx.x < 2) {
        int target = g + threadIdx.x;
        int lo = 0, hi = N;
        while (lo < hi) {
            int mid = (lo + hi) >> 1;
            if (batch[mid] < target) lo = mid + 1; else hi = mid;
        }
        sb[threadIdx.x] = lo;
    }
    __syncthreads();
    const float cntf = fmaxf((float)(sb[1] - sb[0]), 1.f);
    const int c = threadIdx.x;
    float m = pooled[(size_t)g * 128 + c] / cntf;
    float mu = sums[c] * invN;
    float var = sums[128 + c] * invN - mu * mu;
    float sc = gamma[c] * rsqrtf(fmaxf(var, 0.f) + BN_EPS);
    float v = (sc * m + (beta[c] - mu * sc)) * Wp[c];
    // reduce 128 = 2 waves
    const int lane = threadIdx.x & 63;
#pragma unroll
    for (int off = 32; off > 0; off >>= 1) v += __shfl_down(v, off);
    __shared__ float wsum[2];
    if (lane == 0) wsum[threadIdx.x >> 6] = v;
    __syncthreads();
    if (threadIdx.x == 0) out[g] = wsum[0] + wsum[1] + bp[0];
}

// ---------------------------------------------------------------------------
extern "C" void kernel_launch(void* const* d_in, const int* in_sizes, int n_in,
                              void* d_out, int out_size, void* d_ws, size_t ws_size,
                              hipStream_t stream)
{
    const float* x     = (const float*)d_in[0];
    const float* eattr = (const float*)d_in[1];
    const float* W0    = (const float*)d_in[2];
    const float* b0    = (const float*)d_in[3];
    const float* We    = (const float*)d_in[4];
    const float* be    = (const float*)d_in[5];
    const float* W1    = (const float*)d_in[6];
    const float* b1    = (const float*)d_in[7];
    const float* W2    = (const float*)d_in[8];
    const float* b2    = (const float*)d_in[9];
    const float* gamma = (const float*)d_in[10];
    const float* beta  = (const float*)d_in[11];
    const float* Wp    = (const float*)d_in[12];
    const float* bp    = (const float*)d_in[13];
    const int* ei    = (const int*)d_in[14];
    const int* batch = (const int*)d_in[15];

    const int N = in_sizes[0] / 32;   // 50000
    const int E = in_sizes[1] / 16;   // 800000

    char* ws = (char*)d_ws;
    size_t off = 0;
    auto alloc = [&](size_t bytes) { char* p = ws + off; off += (bytes + 255) & ~(size_t)255; return p; };
    unsigned short* Y  = (unsigned short*)alloc((size_t)N * 256 * 2);
    unsigned short* hb = Y;
    float* h2 = (float*)alloc((size_t)N * 128 * 4);
    unsigned short* ag = (unsigned short*)h2;
    float* partial = (float*)alloc(256 * 256 * 4);
    float* sums    = (float*)alloc(256 * 4);
    float* pooled  = (float*)alloc(NGRAPHS * 128 * 4);
    float* mom     = (float*)alloc((size_t)N * 16 * 4);
    unsigned short* W0bf = (unsigned short*)alloc(128 * 32 * 2);
    unsigned short* W1bf = (unsigned short*)alloc(3 * 256 * 128 * 2);
    unsigned short* W2bf = (unsigned short*)alloc(3 * 128 * 256 * 2);
    int* deg_cnt  = (int*)alloc((size_t)N * 4);
    int* rowptr   = (int*)alloc(((size_t)N + 1) * 4);
    int* wp       = (int*)alloc((size_t)N * 4);
    int* blocksum = (int*)alloc(256 * 4);
    int* adjsrc   = (int*)alloc((size_t)E * 4);

    const dim3 blk(256);
    const int mblocks = (N + 63) / 64;
    const int total4 = N * 32;
    const int eblocks = (E + 255) / 256;
    const int sblocks = (N + 255) / 256;   // 196 <= 256
    const float invN = 1.0f / (float)N;

    // --- CSR + edge-attr moments (once, reused by all layers) ---
    hipMemsetAsync(deg_cnt, 0, (size_t)N * 4, stream);
    hipMemsetAsync(mom, 0, (size_t)N * 16 * 4, stream);
    hist_kernel<<<dim3(eblocks), blk, 0, stream>>>(ei, deg_cnt, E);
    scan_part<<<dim3(sblocks), blk, 0, stream>>>(deg_cnt, blocksum, N);
    scan_top<<<dim3(1), blk, 0, stream>>>(blocksum, sblocks);
    scan_emit<<<dim3(sblocks), blk, 0, stream>>>(deg_cnt, blocksum, rowptr, wp, N);
    fill_kernel<<<dim3(eblocks), blk, 0, stream>>>(ei, wp, adjsrc, E);
    mom_scatter<<<dim3((E * 16 + 255) / 256), blk, 0, stream>>>(ei, eattr, mom, E);

    // --- weight pre-conversion (one dispatch) ---
    conv_bf16_3<<<dim3(384), blk, 0, stream>>>(
        W0, W0bf, 128 * 32, W1, W1bf, 3 * 256 * 128, W2, W2bf, 3 * 128 * 256);

    // h = bf16(x @ W0^T + b0)
    gemm_bt<32, false, false, true><<<dim3(mblocks, 2), blk, 0, stream>>>(
        x, W0bf, b0, (void*)hb, N, 128);

    for (int l = 0; l < LAYERS; ++l) {
        aggregate_kernel<<<dim3(2048), blk, 0, stream>>>(
            hb, adjsrc, rowptr, mom, We + l * 128 * 16, be + l * 128, ag, N);
        gemm_bt<128, true, true, true><<<dim3(mblocks, 4), blk, 0, stream>>>(
            ag, W1bf + l * 256 * 128, b1 + l * 256, (void*)Y, N, 256);
        gemm_bt<256, true, false, false><<<dim3(mblocks, 2), blk, 0, stream>>>(
            Y, W2bf + l * 128 * 256, b2 + l * 128, (void*)h2, N, 128);
        bn_stats1<<<dim3(256), blk, 0, stream>>>(h2, partial, N);
        bn_stats2<<<dim3(1), blk, 0, stream>>>(partial, sums, 256);
        if (l < LAYERS - 1)
            bn_apply_bf16<<<dim3(1024), blk, 0, stream>>>(
                h2, sums, gamma + l * 128, beta + l * 128, hb, total4, invN);
    }

    // --- two-stage mean pool + folded final BN + head ---
    hipMemsetAsync(pooled, 0, NGRAPHS * 128 * 4, stream);
    pool_part<<<dim3(784), blk, 0, stream>>>(h2, batch, pooled, N);
    head_final<<<dim3(NGRAPHS), dim3(128), 0, stream>>>(
        pooled, batch, sums, gamma + 2 * 128, beta + 2 * 128, Wp, bp,
        (float*)d_out, N, invN);
}

// Round 7
// 687.926 us; speedup vs baseline: 2.9643x; 1.3959x over previous
//
#include <hip/hip_runtime.h>
#include <stdint.h>

#define EMB 128
#define LAYERS 3
#define NGRAPHS 64
#define BN_EPS 1e-5f

typedef short short8 __attribute__((ext_vector_type(8)));
typedef float float4v __attribute__((ext_vector_type(4)));
typedef unsigned short ushort4v __attribute__((ext_vector_type(4)));

__device__ __forceinline__ unsigned short f2bf(float f) {
    union { float f; unsigned int i; } v; v.f = f;
    unsigned int x = v.i;
    unsigned int r = x + 0x7FFFu + ((x >> 16) & 1u);
    return (unsigned short)(r >> 16);
}
__device__ __forceinline__ float bflo(unsigned int u) {
    union { unsigned int i; float f; } v; v.i = u << 16; return v.f;
}
__device__ __forceinline__ float bfhi(unsigned int u) {
    union { unsigned int i; float f; } v; v.i = u & 0xffff0000u; return v.f;
}
__device__ __forceinline__ unsigned int packbf(float a, float b) {
    return (unsigned int)f2bf(a) | ((unsigned int)f2bf(b) << 16);
}

// f32 -> bf16 (RNE), three concatenated segments in one dispatch
__global__ __launch_bounds__(256) void conv_bf16_3(
    const float* __restrict__ a, unsigned short* __restrict__ oa, int na,
    const float* __restrict__ b, unsigned short* __restrict__ ob, int nb,
    const float* __restrict__ c, unsigned short* __restrict__ oc, int nc)
{
    int i = blockIdx.x * 256 + threadIdx.x;
    int stride = gridDim.x * 256;
    for (int t = i; t < na + nb + nc; t += stride) {
        if (t < na) oa[t] = f2bf(a[t]);
        else if (t < na + nb) ob[t - na] = f2bf(b[t - na]);
        else oc[t - na - nb] = f2bf(c[t - na - nb]);
    }
}

// ---------------------------------------------------------------------------
// GEMM (input embedding only): C = A[M,K] @ B[Ntot,K]^T + bias
// ---------------------------------------------------------------------------
template<int K, bool A_IS_BF16, bool RELU, bool OUT_BF16>
__global__ __launch_bounds__(256) void gemm_bt(
    const void* __restrict__ Av, const unsigned short* __restrict__ B,
    const float* __restrict__ bias, void* __restrict__ Cv,
    int M, int Ntot)
{
    const int wave = threadIdx.x >> 6;
    const int lane = threadIdx.x & 63;
    const int q    = lane >> 4;
    const int ln   = lane & 15;
    const int m_base = blockIdx.x * 64 + wave * 16;
    const int n_base = blockIdx.y * 64;

    float4v acc[4];
#pragma unroll
    for (int i = 0; i < 4; ++i) acc[i] = (float4v){0.f, 0.f, 0.f, 0.f};

    int mrow = m_base + ln;
    if (mrow >= M) mrow = M - 1;

    const int KSTEPS = K / 32;
#pragma unroll
    for (int ks = 0; ks < KSTEPS; ++ks) {
        const int k0 = ks * 32 + q * 8;
        short8 afrag;
        if constexpr (A_IS_BF16) {
            const unsigned short* A = (const unsigned short*)Av;
            afrag = *reinterpret_cast<const short8*>(A + (size_t)mrow * K + k0);
        } else {
            const float* A = (const float*)Av;
            const float4v* p = reinterpret_cast<const float4v*>(A + (size_t)mrow * K + k0);
            float4v f0 = p[0], f1 = p[1];
            afrag[0] = (short)f2bf(f0[0]); afrag[1] = (short)f2bf(f0[1]);
            afrag[2] = (short)f2bf(f0[2]); afrag[3] = (short)f2bf(f0[3]);
            afrag[4] = (short)f2bf(f1[0]); afrag[5] = (short)f2bf(f1[1]);
            afrag[6] = (short)f2bf(f1[2]); afrag[7] = (short)f2bf(f1[3]);
        }
#pragma unroll
        for (int nt = 0; nt < 4; ++nt) {
            const short8 bfrag = *reinterpret_cast<const short8*>(
                B + (size_t)(n_base + nt * 16 + ln) * K + k0);
            acc[nt] = __builtin_amdgcn_mfma_f32_16x16x32_bf16(afrag, bfrag, acc[nt], 0, 0, 0);
        }
    }

#pragma unroll
    for (int nt = 0; nt < 4; ++nt) {
        const int n = n_base + nt * 16 + ln;
        const float bv = bias[n];
#pragma unroll
        for (int r = 0; r < 4; ++r) {
            const int m = m_base + q * 4 + r;
            if (m < M) {
                float v = acc[nt][r] + bv;
                if constexpr (RELU) v = v > 0.f ? v : 0.f;
                if constexpr (OUT_BF16)
                    ((unsigned short*)Cv)[(size_t)m * Ntot + n] = f2bf(v);
                else
                    ((float*)Cv)[(size_t)m * Ntot + n] = v;
            }
        }
    }
}

// ---------------------------------------------------------------------------
// Fused MLP: h2 = (relu(ag@W1^T+b1))@W2^T + b2, plus BN partial stats.
// Block = 64 nodes, 4 waves x 16 nodes. Stage 1 computes Y transposed
// (D[c][node]) so lanes pack 4 consecutive cols -> ds_write_b64; Y tile in
// LDS (stride 264: 132 dwords = 4 mod 32 -> optimal b128 phase tiling).
// Stage 2: A=W2, B=Y(LDS); epilogue writes h2 float4 + shfl-reduced BN
// partials -> LDS -> one global atomicAdd per channel per block.
// ---------------------------------------------------------------------------
__global__ __launch_bounds__(256) void fused_mlp(
    const unsigned short* __restrict__ ag, const unsigned short* __restrict__ W1,
    const float* __restrict__ b1, const unsigned short* __restrict__ W2,
    const float* __restrict__ b2, float* __restrict__ h2,
    float* __restrict__ sums, int M)
{
    __shared__ unsigned short Ylds[64 * 264];
    __shared__ float bnp[256];
    const int tid = threadIdx.x;
    bnp[tid] = 0.f;

    const int wave = tid >> 6, lane = tid & 63;
    const int q = lane >> 4, ln = lane & 15;
    const int node = blockIdx.x * 64 + wave * 16 + ln;
    const int nclamp = (node < M) ? node : (M - 1);
    const int row_l = wave * 16 + ln;
    const int k0 = q * 8;

    // preload ag fragments (B-operand), 4 k-steps
    short8 agf[4];
#pragma unroll
    for (int ks = 0; ks < 4; ++ks)
        agf[ks] = *reinterpret_cast<const short8*>(ag + (size_t)nclamp * 128 + ks * 32 + k0);

    // stage 1: Y (transposed D: rows=cols of Y, cols=nodes)
#pragma unroll
    for (int ct = 0; ct < 16; ++ct) {
        float4v acc = (float4v){0.f, 0.f, 0.f, 0.f};
#pragma unroll
        for (int ks = 0; ks < 4; ++ks) {
            const short8 wf = *reinterpret_cast<const short8*>(
                W1 + (size_t)(ct * 16 + ln) * 128 + ks * 32 + k0);
            acc = __builtin_amdgcn_mfma_f32_16x16x32_bf16(wf, agf[ks], acc, 0, 0, 0);
        }
        const int c0 = ct * 16 + q * 4;
        const float4v bv = *reinterpret_cast<const float4v*>(b1 + c0);
        ushort4v pk;
        pk[0] = f2bf(fmaxf(acc[0] + bv[0], 0.f));
        pk[1] = f2bf(fmaxf(acc[1] + bv[1], 0.f));
        pk[2] = f2bf(fmaxf(acc[2] + bv[2], 0.f));
        pk[3] = f2bf(fmaxf(acc[3] + bv[3], 0.f));
        *reinterpret_cast<ushort4v*>(&Ylds[row_l * 264 + c0]) = pk;
    }
    __syncthreads();

    // stage 2: read own Y rows back as B-operand fragments
    short8 yf[8];
#pragma unroll
    for (int ks = 0; ks < 8; ++ks)
        yf[ks] = *reinterpret_cast<const short8*>(&Ylds[row_l * 264 + ks * 32 + k0]);

    const bool valid = (node < M);
#pragma unroll
    for (int ct = 0; ct < 8; ++ct) {
        float4v acc = (float4v){0.f, 0.f, 0.f, 0.f};
#pragma unroll
        for (int ks = 0; ks < 8; ++ks) {
            const short8 wf = *reinterpret_cast<const short8*>(
                W2 + (size_t)(ct * 16 + ln) * 256 + ks * 32 + k0);
            acc = __builtin_amdgcn_mfma_f32_16x16x32_bf16(wf, yf[ks], acc, 0, 0, 0);
        }
        const int c0 = ct * 16 + q * 4;
        const float4v bv = *reinterpret_cast<const float4v*>(b2 + c0);
        float4v v;
        v[0] = acc[0] + bv[0]; v[1] = acc[1] + bv[1];
        v[2] = acc[2] + bv[2]; v[3] = acc[3] + bv[3];
        if (valid)
            *reinterpret_cast<float4v*>(h2 + (size_t)node * 128 + c0) = v;
        float s[4], s2[4];
#pragma unroll
        for (int r = 0; r < 4; ++r) {
            const float x = valid ? v[r] : 0.f;
            s[r] = x; s2[r] = x * x;
        }
#pragma unroll
        for (int off = 1; off < 16; off <<= 1) {
#pragma unroll
            for (int r = 0; r < 4; ++r) {
                s[r]  += __shfl_xor(s[r],  off);
                s2[r] += __shfl_xor(s2[r], off);
            }
        }
        if (ln == 0) {
#pragma unroll
            for (int r = 0; r < 4; ++r) {
                atomicAdd(&bnp[c0 + r], s[r]);
                atomicAdd(&bnp[128 + c0 + r], s2[r]);
            }
        }
    }
    __syncthreads();
    atomicAdd(&sums[tid], bnp[tid]);
}

// ---------------------------------------------------------------------------
// CSR build: histogram, 3-phase parallel scan, fill (src, edge-id)
// ---------------------------------------------------------------------------
__global__ __launch_bounds__(256) void hist_kernel(
    const int* __restrict__ ei, int* __restrict__ deg_cnt, int E)
{
    int e = blockIdx.x * 256 + threadIdx.x;
    if (e < E) atomicAdd(&deg_cnt[ei[E + e]], 1);
}

__global__ __launch_bounds__(256) void scan_part(
    const int* __restrict__ deg, int* __restrict__ blocksum, int n)
{
    int i = blockIdx.x * 256 + threadIdx.x;
    int v = (i < n) ? deg[i] : 0;
    const int lane = threadIdx.x & 63;
#pragma unroll
    for (int off = 32; off > 0; off >>= 1) v += __shfl_down(v, off);
    __shared__ int ws[4];
    if (lane == 0) ws[threadIdx.x >> 6] = v;
    __syncthreads();
    if (threadIdx.x == 0)
        blocksum[blockIdx.x] = ws[0] + ws[1] + ws[2] + ws[3];
}

__global__ __launch_bounds__(256) void scan_top(
    int* __restrict__ blocksum, int nblk)
{
    const int t = threadIdx.x;
    int v = (t < nblk) ? blocksum[t] : 0;
    const int lane = t & 63, wv = t >> 6;
    int iv = v;
#pragma unroll
    for (int off = 1; off < 64; off <<= 1) {
        int u = __shfl_up(iv, off);
        if (lane >= off) iv += u;
    }
    __shared__ int ws[4];
    if (lane == 63) ws[wv] = iv;
    __syncthreads();
    int woff = 0;
    for (int j = 0; j < wv; ++j) woff += ws[j];
    if (t < nblk) blocksum[t] = woff + iv - v;
}

__global__ __launch_bounds__(256) void scan_emit(
    const int* __restrict__ deg, const int* __restrict__ blockoff,
    int* __restrict__ rowptr, int* __restrict__ wp, int n)
{
    int i = blockIdx.x * 256 + threadIdx.x;
    int v = (i < n) ? deg[i] : 0;
    const int lane = threadIdx.x & 63, wv = threadIdx.x >> 6;
    int iv = v;
#pragma unroll
    for (int off = 1; off < 64; off <<= 1) {
        int u = __shfl_up(iv, off);
        if (lane >= off) iv += u;
    }
    __shared__ int ws[4];
    if (lane == 63) ws[wv] = iv;
    __syncthreads();
    int woff = blockoff[blockIdx.x];
    for (int j = 0; j < wv; ++j) woff += ws[j];
    int ex = woff + iv - v;
    if (i < n) { rowptr[i] = ex; wp[i] = ex; }
    if (i == n - 1) rowptr[n] = ex + v;
}

__global__ __launch_bounds__(256) void fill_kernel(
    const int* __restrict__ ei, int* __restrict__ wp,
    int2* __restrict__ adj, int E)
{
    int e = blockIdx.x * 256 + threadIdx.x;
    if (e < E) {
        int dst = ei[E + e];
        int slot = atomicAdd(&wp[dst], 1);
        adj[slot] = make_int2(ei[e], e);
    }
}

// ---------------------------------------------------------------------------
// mom[n][k] = sum of eattr over in-edges (gather, no atomics).
// Wave per node; 4 edges x 16 channels per iteration; shfl_xor reduce.
// ---------------------------------------------------------------------------
__global__ __launch_bounds__(256) void mom_gather(
    const int2* __restrict__ adj, const int* __restrict__ rowptr,
    const float* __restrict__ eattr, float* __restrict__ mom, int N)
{
    const int lane = threadIdx.x & 63;
    const int gwave = (blockIdx.x * 256 + threadIdx.x) >> 6;
    const int nwaves = (gridDim.x * 256) >> 6;
    const int j = lane >> 4, k = lane & 15;
    for (int n = gwave; n < N; n += nwaves) {
        const int s = rowptr[n], e = rowptr[n + 1];
        float acc = 0.f;
        for (int p = s + j; p < e; p += 4) {
            const int eid = adj[p].y;
            acc += eattr[(size_t)eid * 16 + k];
        }
        acc += __shfl_xor(acc, 16);
        acc += __shfl_xor(acc, 32);
        if (lane < 16) mom[(size_t)n * 16 + lane] = acc;
    }
}

// ---------------------------------------------------------------------------
// Gather aggregation over bf16 h:
// ag[n] = bf16( h[n] + Σ_in h[src] + be*(deg+1) + We·mom[n] )
// ---------------------------------------------------------------------------
__global__ __launch_bounds__(256) void aggregate_kernel(
    const unsigned short* __restrict__ h, const int2* __restrict__ adj,
    const int* __restrict__ rowptr, const float* __restrict__ mom,
    const float* __restrict__ We, const float* __restrict__ be,
    unsigned short* __restrict__ ag, int N)
{
    const int lane = threadIdx.x & 63;
    const int gwave = (blockIdx.x * 256 + threadIdx.x) >> 6;
    const int nwaves = (gridDim.x * 256) >> 6;
    const int c0 = 2 * lane;

    float w0[16], w1[16];
#pragma unroll
    for (int k = 0; k < 16; ++k) {
        w0[k] = We[c0 * 16 + k];
        w1[k] = We[(c0 + 1) * 16 + k];
    }
    const float b0 = be[c0], b1 = be[c0 + 1];

    for (int n = gwave; n < N; n += nwaves) {
        const int s = rowptr[n], e = rowptr[n + 1];
        unsigned int self = *reinterpret_cast<const unsigned int*>(
            h + (size_t)n * 128 + c0);
        float ax = bflo(self), ay = bfhi(self);
        float mval = (lane < 16) ? mom[(size_t)n * 16 + lane] : 0.f;

        int p = s;
        for (; p + 8 <= e; p += 8) {
            int s0 = adj[p].x, s1 = adj[p+1].x, s2 = adj[p+2].x, s3 = adj[p+3].x;
            int s4 = adj[p+4].x, s5 = adj[p+5].x, s6 = adj[p+6].x, s7 = adj[p+7].x;
            unsigned int v0 = *reinterpret_cast<const unsigned int*>(h + (size_t)s0 * 128 + c0);
            unsigned int v1 = *reinterpret_cast<const unsigned int*>(h + (size_t)s1 * 128 + c0);
            unsigned int v2 = *reinterpret_cast<const unsigned int*>(h + (size_t)s2 * 128 + c0);
            unsigned int v3 = *reinterpret_cast<const unsigned int*>(h + (size_t)s3 * 128 + c0);
            unsigned int v4 = *reinterpret_cast<const unsigned int*>(h + (size_t)s4 * 128 + c0);
            unsigned int v5 = *reinterpret_cast<const unsigned int*>(h + (size_t)s5 * 128 + c0);
            unsigned int v6 = *reinterpret_cast<const unsigned int*>(h + (size_t)s6 * 128 + c0);
            unsigned int v7 = *reinterpret_cast<const unsigned int*>(h + (size_t)s7 * 128 + c0);
            ax += bflo(v0) + bflo(v1) + bflo(v2) + bflo(v3)
                + bflo(v4) + bflo(v5) + bflo(v6) + bflo(v7);
            ay += bfhi(v0) + bfhi(v1) + bfhi(v2) + bfhi(v3)
                + bfhi(v4) + bfhi(v5) + bfhi(v6) + bfhi(v7);
        }
        for (; p < e; ++p) {
            int sv = adj[p].x;
            unsigned int v = *reinterpret_cast<const unsigned int*>(
                h + (size_t)sv * 128 + c0);
            ax += bflo(v); ay += bfhi(v);
        }

        const float degp1 = (float)(e - s + 1);
        float d0 = b0 * degp1, d1 = b1 * degp1;
#pragma unroll
        for (int k = 0; k < 16; ++k) {
            const float sk = __shfl(mval, k);
            d0 += w0[k] * sk; d1 += w1[k] * sk;
        }
        ax += d0; ay += d1;
        *reinterpret_cast<unsigned int*>(ag + (size_t)n * 128 + c0) = packbf(ax, ay);
    }
}

// ---------------------------------------------------------------------------
// BN apply + relu -> bf16 h
// ---------------------------------------------------------------------------
__global__ __launch_bounds__(256) void bn_apply_bf16(
    const float* __restrict__ h2, const float* __restrict__ sums,
    const float* __restrict__ gamma, const float* __restrict__ beta,
    unsigned short* __restrict__ h, int total4, float invN)
{
    int tid = blockIdx.x * 256 + threadIdx.x;
    int c4 = (tid * 4) & 127;
    float sc[4], sh[4];
#pragma unroll
    for (int j = 0; j < 4; ++j) {
        int c = c4 + j;
        float mu = sums[c] * invN;
        float var = sums[128 + c] * invN - mu * mu;
        float s = gamma[c] * rsqrtf(fmaxf(var, 0.f) + BN_EPS);
        sc[j] = s;
        sh[j] = beta[c] - mu * s;
    }
    int stride = gridDim.x * 256;
    for (int i = tid; i < total4; i += stride) {
        float4v v = reinterpret_cast<const float4v*>(h2)[i];
        float x0 = fmaxf(sc[0] * v[0] + sh[0], 0.f);
        float x1 = fmaxf(sc[1] * v[1] + sh[1], 0.f);
        float x2 = fmaxf(sc[2] * v[2] + sh[2], 0.f);
        float x3 = fmaxf(sc[3] * v[3] + sh[3], 0.f);
        uint2 o; o.x = packbf(x0, x1); o.y = packbf(x2, x3);
        reinterpret_cast<uint2*>(h)[i] = o;
    }
}

// ---------------------------------------------------------------------------
// Pool stage 1: segmented sum over sorted batch keys
// ---------------------------------------------------------------------------
__global__ __launch_bounds__(256) void pool_part(
    const float* __restrict__ h2, const int* __restrict__ batch,
    float* __restrict__ pooled, int N)
{
    const int per = (N + gridDim.x - 1) / gridDim.x;
    const int start = blockIdx.x * per;
    const int end = min(start + per, N);
    if (start >= end) return;
    const int c = threadIdx.x & 127;
    const int sub = threadIdx.x >> 7;
    int g_cur = batch[start];
    float acc = 0.f;
    for (int n = start + sub; n < end; n += 2) {
        int g = batch[n];
        if (g != g_cur) {
            if (acc != 0.f) atomicAdd(&pooled[(size_t)g_cur * 128 + c], acc);
            acc = 0.f; g_cur = g;
        }
        acc += h2[(size_t)n * 128 + c];
    }
    if (acc != 0.f) atomicAdd(&pooled[(size_t)g_cur * 128 + c], acc);
}

// ---------------------------------------------------------------------------
// Pool stage 2: mean + folded final BN affine + head dot
// ---------------------------------------------------------------------------
__global__ __launch_bounds__(128) void head_final(
    const float* __restrict__ pooled, const int* __restrict__ batch,
    const float* __restrict__ sums, const float* __restrict__ gamma,
    const float* __restrict__ beta, const float* __restrict__ Wp,
    const float* __restrict__ bp, float* __restrict__ out, int N, float invN)
{
    const int g = blockIdx.x;
    __shared__ int sb[2];
    if (threadIdx.x < 2) {
        int target = g + threadIdx.x;
        int lo = 0, hi = N;
        while (lo < hi) {
            int mid = (lo + hi) >> 1;
            if (batch[mid] < target) lo = mid + 1; else hi = mid;
        }
        sb[threadIdx.x] = lo;
    }
    __syncthreads();
    const float cntf = fmaxf((float)(sb[1] - sb[0]), 1.f);
    const int c = threadIdx.x;
    float m = pooled[(size_t)g * 128 + c] / cntf;
    float mu = sums[c] * invN;
    float var = sums[128 + c] * invN - mu * mu;
    float sc = gamma[c] * rsqrtf(fmaxf(var, 0.f) + BN_EPS);
    float v = (sc * m + (beta[c] - mu * sc)) * Wp[c];
    const int lane = threadIdx.x & 63;
#pragma unroll
    for (int off = 32; off > 0; off >>= 1) v += __shfl_down(v, off);
    __shared__ float wsum[2];
    if (lane == 0) wsum[threadIdx.x >> 6] = v;
    __syncthreads();
    if (threadIdx.x == 0) out[g] = wsum[0] + wsum[1] + bp[0];
}

// ---------------------------------------------------------------------------
extern "C" void kernel_launch(void* const* d_in, const int* in_sizes, int n_in,
                              void* d_out, int out_size, void* d_ws, size_t ws_size,
                              hipStream_t stream)
{
    const float* x     = (const float*)d_in[0];
    const float* eattr = (const float*)d_in[1];
    const float* W0    = (const float*)d_in[2];
    const float* b0    = (const float*)d_in[3];
    const float* We    = (const float*)d_in[4];
    const float* be    = (const float*)d_in[5];
    const float* W1    = (const float*)d_in[6];
    const float* b1    = (const float*)d_in[7];
    const float* W2    = (const float*)d_in[8];
    const float* b2    = (const float*)d_in[9];
    const float* gamma = (const float*)d_in[10];
    const float* beta  = (const float*)d_in[11];
    const float* Wp    = (const float*)d_in[12];
    const float* bp    = (const float*)d_in[13];
    const int* ei    = (const int*)d_in[14];
    const int* batch = (const int*)d_in[15];

    const int N = in_sizes[0] / 32;   // 50000
    const int E = in_sizes[1] / 16;   // 800000

    char* ws = (char*)d_ws;
    size_t off = 0;
    auto alloc = [&](size_t bytes) { char* p = ws + off; off += (bytes + 255) & ~(size_t)255; return p; };
    unsigned short* hb = (unsigned short*)alloc((size_t)N * 128 * 2);
    unsigned short* ag = (unsigned short*)alloc((size_t)N * 128 * 2);
    float* h2 = (float*)alloc((size_t)N * 128 * 4);
    // deg_cnt / wp alias h2 (dead before first fused_mlp write)
    int* deg_cnt = (int*)h2;
    int* wp      = ((int*)h2) + N;
    float* sums    = (float*)alloc(256 * 4);
    float* pooled  = (float*)alloc(NGRAPHS * 128 * 4);
    float* mom     = (float*)alloc((size_t)N * 16 * 4);
    unsigned short* W0bf = (unsigned short*)alloc(128 * 32 * 2);
    unsigned short* W1bf = (unsigned short*)alloc(3 * 256 * 128 * 2);
    unsigned short* W2bf = (unsigned short*)alloc(3 * 128 * 256 * 2);
    int* rowptr   = (int*)alloc(((size_t)N + 1) * 4);
    int* blocksum = (int*)alloc(256 * 4);
    int2* adj     = (int2*)alloc((size_t)E * 8);

    const dim3 blk(256);
    const int mblocks = (N + 63) / 64;
    const int total4 = N * 32;
    const int eblocks = (E + 255) / 256;
    const int sblocks = (N + 255) / 256;   // <=256
    const float invN = 1.0f / (float)N;

    // --- CSR + edge-attr moments (once, reused by all layers) ---
    hipMemsetAsync(deg_cnt, 0, (size_t)N * 4, stream);
    hist_kernel<<<dim3(eblocks), blk, 0, stream>>>(ei, deg_cnt, E);
    scan_part<<<dim3(sblocks), blk, 0, stream>>>(deg_cnt, blocksum, N);
    scan_top<<<dim3(1), blk, 0, stream>>>(blocksum, sblocks);
    scan_emit<<<dim3(sblocks), blk, 0, stream>>>(deg_cnt, blocksum, rowptr, wp, N);
    fill_kernel<<<dim3(eblocks), blk, 0, stream>>>(ei, wp, adj, E);
    mom_gather<<<dim3(2048), blk, 0, stream>>>(adj, rowptr, eattr, mom, N);

    // --- weight pre-conversion ---
    conv_bf16_3<<<dim3(384), blk, 0, stream>>>(
        W0, W0bf, 128 * 32, W1, W1bf, 3 * 256 * 128, W2, W2bf, 3 * 128 * 256);

    // h = bf16(x @ W0^T + b0)
    gemm_bt<32, false, false, true><<<dim3(mblocks, 2), blk, 0, stream>>>(
        x, W0bf, b0, (void*)hb, N, 128);

    for (int l = 0; l < LAYERS; ++l) {
        hipMemsetAsync(sums, 0, 256 * 4, stream);
        aggregate_kernel<<<dim3(2048), blk, 0, stream>>>(
            hb, adj, rowptr, mom, We + l * 128 * 16, be + l * 128, ag, N);
        fused_mlp<<<dim3(mblocks), blk, 0, stream>>>(
            ag, W1bf + l * 256 * 128, b1 + l * 256,
            W2bf + l * 128 * 256, b2 + l * 128, h2, sums, N);
        if (l < LAYERS - 1)
            bn_apply_bf16<<<dim3(1024), blk, 0, stream>>>(
                h2, sums, gamma + l * 128, beta + l * 128, hb, total4, invN);
    }

    // --- two-stage mean pool + folded final BN + head ---
    hipMemsetAsync(pooled, 0, NGRAPHS * 128 * 4, stream);
    pool_part<<<dim3(784), blk, 0, stream>>>(h2, batch, pooled, N);
    head_final<<<dim3(NGRAPHS), dim3(128), 0, stream>>>(
        pooled, batch, sums, gamma + 2 * 128, beta + 2 * 128, Wp, bp,
        (float*)d_out, N, invN);
}

// Round 8
// 661.426 us; speedup vs baseline: 3.0831x; 1.0401x over previous
//
#include <hip/hip_runtime.h>
#include <stdint.h>

#define EMB 128
#define LAYERS 3
#define NGRAPHS 64
#define BN_EPS 1e-5f

typedef short short8 __attribute__((ext_vector_type(8)));
typedef float float4v __attribute__((ext_vector_type(4)));
typedef unsigned short ushort4v __attribute__((ext_vector_type(4)));

__device__ __forceinline__ unsigned short f2bf(float f) {
    union { float f; unsigned int i; } v; v.f = f;
    unsigned int x = v.i;
    unsigned int r = x + 0x7FFFu + ((x >> 16) & 1u);
    return (unsigned short)(r >> 16);
}
__device__ __forceinline__ float bflo(unsigned int u) {
    union { unsigned int i; float f; } v; v.i = u << 16; return v.f;
}
__device__ __forceinline__ float bfhi(unsigned int u) {
    union { unsigned int i; float f; } v; v.i = u & 0xffff0000u; return v.f;
}
__device__ __forceinline__ unsigned int packbf(float a, float b) {
    return (unsigned int)f2bf(a) | ((unsigned int)f2bf(b) << 16);
}

// f32 -> bf16 (RNE), three concatenated segments in one dispatch
__global__ __launch_bounds__(256) void conv_bf16_3(
    const float* __restrict__ a, unsigned short* __restrict__ oa, int na,
    const float* __restrict__ b, unsigned short* __restrict__ ob, int nb,
    const float* __restrict__ c, unsigned short* __restrict__ oc, int nc)
{
    int i = blockIdx.x * 256 + threadIdx.x;
    int stride = gridDim.x * 256;
    for (int t = i; t < na + nb + nc; t += stride) {
        if (t < na) oa[t] = f2bf(a[t]);
        else if (t < na + nb) ob[t - na] = f2bf(b[t - na]);
        else oc[t - na - nb] = f2bf(c[t - na - nb]);
    }
}

// ---------------------------------------------------------------------------
// GEMM (input embedding only): C = A[M,K] @ B[Ntot,K]^T + bias
// ---------------------------------------------------------------------------
template<int K, bool A_IS_BF16, bool RELU, bool OUT_BF16>
__global__ __launch_bounds__(256) void gemm_bt(
    const void* __restrict__ Av, const unsigned short* __restrict__ B,
    const float* __restrict__ bias, void* __restrict__ Cv,
    int M, int Ntot)
{
    const int wave = threadIdx.x >> 6;
    const int lane = threadIdx.x & 63;
    const int q    = lane >> 4;
    const int ln   = lane & 15;
    const int m_base = blockIdx.x * 64 + wave * 16;
    const int n_base = blockIdx.y * 64;

    float4v acc[4];
#pragma unroll
    for (int i = 0; i < 4; ++i) acc[i] = (float4v){0.f, 0.f, 0.f, 0.f};

    int mrow = m_base + ln;
    if (mrow >= M) mrow = M - 1;

    const int KSTEPS = K / 32;
#pragma unroll
    for (int ks = 0; ks < KSTEPS; ++ks) {
        const int k0 = ks * 32 + q * 8;
        short8 afrag;
        if constexpr (A_IS_BF16) {
            const unsigned short* A = (const unsigned short*)Av;
            afrag = *reinterpret_cast<const short8*>(A + (size_t)mrow * K + k0);
        } else {
            const float* A = (const float*)Av;
            const float4v* p = reinterpret_cast<const float4v*>(A + (size_t)mrow * K + k0);
            float4v f0 = p[0], f1 = p[1];
            afrag[0] = (short)f2bf(f0[0]); afrag[1] = (short)f2bf(f0[1]);
            afrag[2] = (short)f2bf(f0[2]); afrag[3] = (short)f2bf(f0[3]);
            afrag[4] = (short)f2bf(f1[0]); afrag[5] = (short)f2bf(f1[1]);
            afrag[6] = (short)f2bf(f1[2]); afrag[7] = (short)f2bf(f1[3]);
        }
#pragma unroll
        for (int nt = 0; nt < 4; ++nt) {
            const short8 bfrag = *reinterpret_cast<const short8*>(
                B + (size_t)(n_base + nt * 16 + ln) * K + k0);
            acc[nt] = __builtin_amdgcn_mfma_f32_16x16x32_bf16(afrag, bfrag, acc[nt], 0, 0, 0);
        }
    }

#pragma unroll
    for (int nt = 0; nt < 4; ++nt) {
        const int n = n_base + nt * 16 + ln;
        const float bv = bias[n];
#pragma unroll
        for (int r = 0; r < 4; ++r) {
            const int m = m_base + q * 4 + r;
            if (m < M) {
                float v = acc[nt][r] + bv;
                if constexpr (RELU) v = v > 0.f ? v : 0.f;
                if constexpr (OUT_BF16)
                    ((unsigned short*)Cv)[(size_t)m * Ntot + n] = f2bf(v);
                else
                    ((float*)Cv)[(size_t)m * Ntot + n] = v;
            }
        }
    }
}

// ---------------------------------------------------------------------------
// Fused MLP v2: 1-wave blocks, 16 nodes each (grid ~3125 for TLP).
// h2 = (relu(ag@W1^T+b1))@W2^T + b2, plus striped BN partial stats.
// Stage 1 computes Y transposed into an 8.4 KB LDS tile (stride 264),
// stage 2 reads it back as B-fragments. Stats: shfl-reduce over the 16
// nodes, atomicAdd into sums2[blockIdx&31][256] (32-way striping).
// ---------------------------------------------------------------------------
__global__ __launch_bounds__(64) void fused_mlp(
    const unsigned short* __restrict__ ag, const unsigned short* __restrict__ W1,
    const float* __restrict__ b1, const unsigned short* __restrict__ W2,
    const float* __restrict__ b2, float* __restrict__ h2,
    float* __restrict__ sums2, int M)
{
    __shared__ unsigned short Ylds[16 * 264];
    const int lane = threadIdx.x;
    const int q = lane >> 4, ln = lane & 15;
    const int node = blockIdx.x * 16 + ln;
    const int nclamp = (node < M) ? node : (M - 1);
    const int k0 = q * 8;
    float* slice = sums2 + (size_t)(blockIdx.x & 31) * 256;

    // preload ag fragments (B-operand), 4 k-steps
    short8 agf[4];
#pragma unroll
    for (int ks = 0; ks < 4; ++ks)
        agf[ks] = *reinterpret_cast<const short8*>(ag + (size_t)nclamp * 128 + ks * 32 + k0);

    // stage 1: Y transposed (rows = channels, cols = nodes)
#pragma unroll
    for (int ct = 0; ct < 16; ++ct) {
        float4v acc = (float4v){0.f, 0.f, 0.f, 0.f};
#pragma unroll
        for (int ks = 0; ks < 4; ++ks) {
            const short8 wf = *reinterpret_cast<const short8*>(
                W1 + (size_t)(ct * 16 + ln) * 128 + ks * 32 + k0);
            acc = __builtin_amdgcn_mfma_f32_16x16x32_bf16(wf, agf[ks], acc, 0, 0, 0);
        }
        const int c0 = ct * 16 + q * 4;
        const float4v bv = *reinterpret_cast<const float4v*>(b1 + c0);
        ushort4v pk;
        pk[0] = f2bf(fmaxf(acc[0] + bv[0], 0.f));
        pk[1] = f2bf(fmaxf(acc[1] + bv[1], 0.f));
        pk[2] = f2bf(fmaxf(acc[2] + bv[2], 0.f));
        pk[3] = f2bf(fmaxf(acc[3] + bv[3], 0.f));
        *reinterpret_cast<ushort4v*>(&Ylds[ln * 264 + c0]) = pk;
    }
    __syncthreads();

    // stage 2: read own Y row back as B-operand fragments
    short8 yf[8];
#pragma unroll
    for (int ks = 0; ks < 8; ++ks)
        yf[ks] = *reinterpret_cast<const short8*>(&Ylds[ln * 264 + ks * 32 + k0]);

    const bool valid = (node < M);
#pragma unroll
    for (int ct = 0; ct < 8; ++ct) {
        float4v acc = (float4v){0.f, 0.f, 0.f, 0.f};
#pragma unroll
        for (int ks = 0; ks < 8; ++ks) {
            const short8 wf = *reinterpret_cast<const short8*>(
                W2 + (size_t)(ct * 16 + ln) * 256 + ks * 32 + k0);
            acc = __builtin_amdgcn_mfma_f32_16x16x32_bf16(wf, yf[ks], acc, 0, 0, 0);
        }
        const int c0 = ct * 16 + q * 4;
        const float4v bv = *reinterpret_cast<const float4v*>(b2 + c0);
        float4v v;
        v[0] = acc[0] + bv[0]; v[1] = acc[1] + bv[1];
        v[2] = acc[2] + bv[2]; v[3] = acc[3] + bv[3];
        if (valid)
            *reinterpret_cast<float4v*>(h2 + (size_t)node * 128 + c0) = v;
        float s[4], s2[4];
#pragma unroll
        for (int r = 0; r < 4; ++r) {
            const float x = valid ? v[r] : 0.f;
            s[r] = x; s2[r] = x * x;
        }
#pragma unroll
        for (int off = 1; off < 16; off <<= 1) {
#pragma unroll
            for (int r = 0; r < 4; ++r) {
                s[r]  += __shfl_xor(s[r],  off);
                s2[r] += __shfl_xor(s2[r], off);
            }
        }
        if (ln == 0) {
#pragma unroll
            for (int r = 0; r < 4; ++r) {
                atomicAdd(&slice[c0 + r], s[r]);
                atomicAdd(&slice[128 + c0 + r], s2[r]);
            }
        }
    }
}

// ---------------------------------------------------------------------------
// Fold 32 striped stat slices into per-channel BN (scale, shift)
// ---------------------------------------------------------------------------
__global__ __launch_bounds__(128) void bn_coef(
    const float* __restrict__ sums2, const float* __restrict__ gamma,
    const float* __restrict__ beta, float* __restrict__ coef, float invN)
{
    const int c = threadIdx.x;
    float s = 0.f, ss = 0.f;
    for (int k = 0; k < 32; ++k) {
        s  += sums2[k * 256 + c];
        ss += sums2[k * 256 + 128 + c];
    }
    float mu = s * invN;
    float var = ss * invN - mu * mu;
    float sc = gamma[c] * rsqrtf(fmaxf(var, 0.f) + BN_EPS);
    coef[c] = sc;
    coef[128 + c] = beta[c] - mu * sc;
}

// ---------------------------------------------------------------------------
// CSR build: histogram, 3-phase parallel scan, fill (src, edge-id)
// ---------------------------------------------------------------------------
__global__ __launch_bounds__(256) void hist_kernel(
    const int* __restrict__ ei, int* __restrict__ deg_cnt, int E)
{
    int e = blockIdx.x * 256 + threadIdx.x;
    if (e < E) atomicAdd(&deg_cnt[ei[E + e]], 1);
}

__global__ __launch_bounds__(256) void scan_part(
    const int* __restrict__ deg, int* __restrict__ blocksum, int n)
{
    int i = blockIdx.x * 256 + threadIdx.x;
    int v = (i < n) ? deg[i] : 0;
    const int lane = threadIdx.x & 63;
#pragma unroll
    for (int off = 32; off > 0; off >>= 1) v += __shfl_down(v, off);
    __shared__ int ws[4];
    if (lane == 0) ws[threadIdx.x >> 6] = v;
    __syncthreads();
    if (threadIdx.x == 0)
        blocksum[blockIdx.x] = ws[0] + ws[1] + ws[2] + ws[3];
}

__global__ __launch_bounds__(256) void scan_top(
    int* __restrict__ blocksum, int nblk)
{
    const int t = threadIdx.x;
    int v = (t < nblk) ? blocksum[t] : 0;
    const int lane = t & 63, wv = t >> 6;
    int iv = v;
#pragma unroll
    for (int off = 1; off < 64; off <<= 1) {
        int u = __shfl_up(iv, off);
        if (lane >= off) iv += u;
    }
    __shared__ int ws[4];
    if (lane == 63) ws[wv] = iv;
    __syncthreads();
    int woff = 0;
    for (int j = 0; j < wv; ++j) woff += ws[j];
    if (t < nblk) blocksum[t] = woff + iv - v;
}

__global__ __launch_bounds__(256) void scan_emit(
    const int* __restrict__ deg, const int* __restrict__ blockoff,
    int* __restrict__ rowptr, int* __restrict__ wp, int n)
{
    int i = blockIdx.x * 256 + threadIdx.x;
    int v = (i < n) ? deg[i] : 0;
    const int lane = threadIdx.x & 63, wv = threadIdx.x >> 6;
    int iv = v;
#pragma unroll
    for (int off = 1; off < 64; off <<= 1) {
        int u = __shfl_up(iv, off);
        if (lane >= off) iv += u;
    }
    __shared__ int ws[4];
    if (lane == 63) ws[wv] = iv;
    __syncthreads();
    int woff = blockoff[blockIdx.x];
    for (int j = 0; j < wv; ++j) woff += ws[j];
    int ex = woff + iv - v;
    if (i < n) { rowptr[i] = ex; wp[i] = ex; }
    if (i == n - 1) rowptr[n] = ex + v;
}

__global__ __launch_bounds__(256) void fill_kernel(
    const int* __restrict__ ei, int* __restrict__ wp,
    int2* __restrict__ adj, int E)
{
    int e = blockIdx.x * 256 + threadIdx.x;
    if (e < E) {
        int dst = ei[E + e];
        int slot = atomicAdd(&wp[dst], 1);
        adj[slot] = make_int2(ei[e], e);
    }
}

// ---------------------------------------------------------------------------
// mom[n][k] = sum of eattr over in-edges (gather, no atomics)
// ---------------------------------------------------------------------------
__global__ __launch_bounds__(256) void mom_gather(
    const int2* __restrict__ adj, const int* __restrict__ rowptr,
    const float* __restrict__ eattr, float* __restrict__ mom, int N)
{
    const int lane = threadIdx.x & 63;
    const int gwave = (blockIdx.x * 256 + threadIdx.x) >> 6;
    const int nwaves = (gridDim.x * 256) >> 6;
    const int j = lane >> 4, k = lane & 15;
    for (int n = gwave; n < N; n += nwaves) {
        const int s = rowptr[n], e = rowptr[n + 1];
        float acc = 0.f;
        for (int p = s + j; p < e; p += 4) {
            const int eid = adj[p].y;
            acc += eattr[(size_t)eid * 16 + k];
        }
        acc += __shfl_xor(acc, 16);
        acc += __shfl_xor(acc, 32);
        if (lane < 16) mom[(size_t)n * 16 + lane] = acc;
    }
}

// ---------------------------------------------------------------------------
// Gather aggregation over bf16 h:
// ag[n] = bf16( h[n] + Σ_in h[src] + be*(deg+1) + We·mom[n] )
// ---------------------------------------------------------------------------
__global__ __launch_bounds__(256) void aggregate_kernel(
    const unsigned short* __restrict__ h, const int2* __restrict__ adj,
    const int* __restrict__ rowptr, const float* __restrict__ mom,
    const float* __restrict__ We, const float* __restrict__ be,
    unsigned short* __restrict__ ag, int N)
{
    const int lane = threadIdx.x & 63;
    const int gwave = (blockIdx.x * 256 + threadIdx.x) >> 6;
    const int nwaves = (gridDim.x * 256) >> 6;
    const int c0 = 2 * lane;

    float w0[16], w1[16];
#pragma unroll
    for (int k = 0; k < 16; ++k) {
        w0[k] = We[c0 * 16 + k];
        w1[k] = We[(c0 + 1) * 16 + k];
    }
    const float b0 = be[c0], b1 = be[c0 + 1];

    for (int n = gwave; n < N; n += nwaves) {
        const int s = rowptr[n], e = rowptr[n + 1];
        unsigned int self = *reinterpret_cast<const unsigned int*>(
            h + (size_t)n * 128 + c0);
        float ax = bflo(self), ay = bfhi(self);
        float mval = (lane < 16) ? mom[(size_t)n * 16 + lane] : 0.f;

        int p = s;
        for (; p + 8 <= e; p += 8) {
            int s0 = adj[p].x, s1 = adj[p+1].x, s2 = adj[p+2].x, s3 = adj[p+3].x;
            int s4 = adj[p+4].x, s5 = adj[p+5].x, s6 = adj[p+6].x, s7 = adj[p+7].x;
            unsigned int v0 = *reinterpret_cast<const unsigned int*>(h + (size_t)s0 * 128 + c0);
            unsigned int v1 = *reinterpret_cast<const unsigned int*>(h + (size_t)s1 * 128 + c0);
            unsigned int v2 = *reinterpret_cast<const unsigned int*>(h + (size_t)s2 * 128 + c0);
            unsigned int v3 = *reinterpret_cast<const unsigned int*>(h + (size_t)s3 * 128 + c0);
            unsigned int v4 = *reinterpret_cast<const unsigned int*>(h + (size_t)s4 * 128 + c0);
            unsigned int v5 = *reinterpret_cast<const unsigned int*>(h + (size_t)s5 * 128 + c0);
            unsigned int v6 = *reinterpret_cast<const unsigned int*>(h + (size_t)s6 * 128 + c0);
            unsigned int v7 = *reinterpret_cast<const unsigned int*>(h + (size_t)s7 * 128 + c0);
            ax += bflo(v0) + bflo(v1) + bflo(v2) + bflo(v3)
                + bflo(v4) + bflo(v5) + bflo(v6) + bflo(v7);
            ay += bfhi(v0) + bfhi(v1) + bfhi(v2) + bfhi(v3)
                + bfhi(v4) + bfhi(v5) + bfhi(v6) + bfhi(v7);
        }
        for (; p < e; ++p) {
            int sv = adj[p].x;
            unsigned int v = *reinterpret_cast<const unsigned int*>(
                h + (size_t)sv * 128 + c0);
            ax += bflo(v); ay += bfhi(v);
        }

        const float degp1 = (float)(e - s + 1);
        float d0 = b0 * degp1, d1 = b1 * degp1;
#pragma unroll
        for (int k = 0; k < 16; ++k) {
            const float sk = __shfl(mval, k);
            d0 += w0[k] * sk; d1 += w1[k] * sk;
        }
        ax += d0; ay += d1;
        *reinterpret_cast<unsigned int*>(ag + (size_t)n * 128 + c0) = packbf(ax, ay);
    }
}

// ---------------------------------------------------------------------------
// BN apply + relu -> bf16 h  (uses precomputed coef)
// ---------------------------------------------------------------------------
__global__ __launch_bounds__(256) void bn_apply_bf16(
    const float* __restrict__ h2, const float* __restrict__ coef,
    unsigned short* __restrict__ h, int total4)
{
    int tid = blockIdx.x * 256 + threadIdx.x;
    int c4 = (tid * 4) & 127;
    float sc[4], sh[4];
#pragma unroll
    for (int j = 0; j < 4; ++j) {
        sc[j] = coef[c4 + j];
        sh[j] = coef[128 + c4 + j];
    }
    int stride = gridDim.x * 256;
    for (int i = tid; i < total4; i += stride) {
        float4v v = reinterpret_cast<const float4v*>(h2)[i];
        float x0 = fmaxf(sc[0] * v[0] + sh[0], 0.f);
        float x1 = fmaxf(sc[1] * v[1] + sh[1], 0.f);
        float x2 = fmaxf(sc[2] * v[2] + sh[2], 0.f);
        float x3 = fmaxf(sc[3] * v[3] + sh[3], 0.f);
        uint2 o; o.x = packbf(x0, x1); o.y = packbf(x2, x3);
        reinterpret_cast<uint2*>(h)[i] = o;
    }
}

// ---------------------------------------------------------------------------
// Pool stage 1: segmented sum over sorted batch keys
// ---------------------------------------------------------------------------
__global__ __launch_bounds__(256) void pool_part(
    const float* __restrict__ h2, const int* __restrict__ batch,
    float* __restrict__ pooled, int N)
{
    const int per = (N + gridDim.x - 1) / gridDim.x;
    const int start = blockIdx.x * per;
    const int end = min(start + per, N);
    if (start >= end) return;
    const int c = threadIdx.x & 127;
    const int sub = threadIdx.x >> 7;
    int g_cur = batch[start];
    float acc = 0.f;
    for (int n = start + sub; n < end; n += 2) {
        int g = batch[n];
        if (g != g_cur) {
            if (acc != 0.f) atomicAdd(&pooled[(size_t)g_cur * 128 + c], acc);
            acc = 0.f; g_cur = g;
        }
        acc += h2[(size_t)n * 128 + c];
    }
    if (acc != 0.f) atomicAdd(&pooled[(size_t)g_cur * 128 + c], acc);
}

// ---------------------------------------------------------------------------
// Pool stage 2: mean + folded final BN affine (coef) + head dot
// ---------------------------------------------------------------------------
__global__ __launch_bounds__(128) void head_final(
    const float* __restrict__ pooled, const int* __restrict__ batch,
    const float* __restrict__ coef, const float* __restrict__ Wp,
    const float* __restrict__ bp, float* __restrict__ out, int N)
{
    const int g = blockIdx.x;
    __shared__ int sb[2];
    if (threadIdx.x < 2) {
        int target = g + threadIdx.x;
        int lo = 0, hi = N;
        while (lo < hi) {
            int mid = (lo + hi) >> 1;
            if (batch[mid] < target) lo = mid + 1; else hi = mid;
        }
        sb[threadIdx.x] = lo;
    }
    __syncthreads();
    const float cntf = fmaxf((float)(sb[1] - sb[0]), 1.f);
    const int c = threadIdx.x;
    float m = pooled[(size_t)g * 128 + c] / cntf;
    float v = (coef[c] * m + coef[128 + c]) * Wp[c];
    const int lane = threadIdx.x & 63;
#pragma unroll
    for (int off = 32; off > 0; off >>= 1) v += __shfl_down(v, off);
    __shared__ float wsum[2];
    if (lane == 0) wsum[threadIdx.x >> 6] = v;
    __syncthreads();
    if (threadIdx.x == 0) out[g] = wsum[0] + wsum[1] + bp[0];
}

// ---------------------------------------------------------------------------
extern "C" void kernel_launch(void* const* d_in, const int* in_sizes, int n_in,
                              void* d_out, int out_size, void* d_ws, size_t ws_size,
                              hipStream_t stream)
{
    const float* x     = (const float*)d_in[0];
    const float* eattr = (const float*)d_in[1];
    const float* W0    = (const float*)d_in[2];
    const float* b0    = (const float*)d_in[3];
    const float* We    = (const float*)d_in[4];
    const float* be    = (const float*)d_in[5];
    const float* W1    = (const float*)d_in[6];
    const float* b1    = (const float*)d_in[7];
    const float* W2    = (const float*)d_in[8];
    const float* b2    = (const float*)d_in[9];
    const float* gamma = (const float*)d_in[10];
    const float* beta  = (const float*)d_in[11];
    const float* Wp    = (const float*)d_in[12];
    const float* bp    = (const float*)d_in[13];
    const int* ei    = (const int*)d_in[14];
    const int* batch = (const int*)d_in[15];

    const int N = in_sizes[0] / 32;   // 50000
    const int E = in_sizes[1] / 16;   // 800000

    char* ws = (char*)d_ws;
    size_t off = 0;
    auto alloc = [&](size_t bytes) { char* p = ws + off; off += (bytes + 255) & ~(size_t)255; return p; };
    unsigned short* hb = (unsigned short*)alloc((size_t)N * 128 * 2);
    unsigned short* ag = (unsigned short*)alloc((size_t)N * 128 * 2);
    float* h2 = (float*)alloc((size_t)N * 128 * 4);
    // deg_cnt / wp alias h2 (dead before first fused_mlp write)
    int* deg_cnt = (int*)h2;
    int* wp      = ((int*)h2) + N;
    float* sums2   = (float*)alloc(32 * 256 * 4);
    float* coef    = (float*)alloc(256 * 4);
    float* pooled  = (float*)alloc(NGRAPHS * 128 * 4);
    float* mom     = (float*)alloc((size_t)N * 16 * 4);
    unsigned short* W0bf = (unsigned short*)alloc(128 * 32 * 2);
    unsigned short* W1bf = (unsigned short*)alloc(3 * 256 * 128 * 2);
    unsigned short* W2bf = (unsigned short*)alloc(3 * 128 * 256 * 2);
    int* rowptr   = (int*)alloc(((size_t)N + 1) * 4);
    int* blocksum = (int*)alloc(256 * 4);
    int2* adj     = (int2*)alloc((size_t)E * 8);

    const dim3 blk(256);
    const int mblocks = (N + 63) / 64;
    const int nb16 = (N + 15) / 16;
    const int total4 = N * 32;
    const int eblocks = (E + 255) / 256;
    const int sblocks = (N + 255) / 256;   // <=256
    const float invN = 1.0f / (float)N;

    // --- CSR + edge-attr moments (once, reused by all layers) ---
    hipMemsetAsync(deg_cnt, 0, (size_t)N * 4, stream);
    hist_kernel<<<dim3(eblocks), blk, 0, stream>>>(ei, deg_cnt, E);
    scan_part<<<dim3(sblocks), blk, 0, stream>>>(deg_cnt, blocksum, N);
    scan_top<<<dim3(1), blk, 0, stream>>>(blocksum, sblocks);
    scan_emit<<<dim3(sblocks), blk, 0, stream>>>(deg_cnt, blocksum, rowptr, wp, N);
    fill_kernel<<<dim3(eblocks), blk, 0, stream>>>(ei, wp, adj, E);
    mom_gather<<<dim3(2048), blk, 0, stream>>>(adj, rowptr, eattr, mom, N);

    // --- weight pre-conversion ---
    conv_bf16_3<<<dim3(384), blk, 0, stream>>>(
        W0, W0bf, 128 * 32, W1, W1bf, 3 * 256 * 128, W2, W2bf, 3 * 128 * 256);

    // h = bf16(x @ W0^T + b0)
    gemm_bt<32, false, false, true><<<dim3(mblocks, 2), blk, 0, stream>>>(
        x, W0bf, b0, (void*)hb, N, 128);

    for (int l = 0; l < LAYERS; ++l) {
        hipMemsetAsync(sums2, 0, 32 * 256 * 4, stream);
        aggregate_kernel<<<dim3(2048), blk, 0, stream>>>(
            hb, adj, rowptr, mom, We + l * 128 * 16, be + l * 128, ag, N);
        fused_mlp<<<dim3(nb16), dim3(64), 0, stream>>>(
            ag, W1bf + l * 256 * 128, b1 + l * 256,
            W2bf + l * 128 * 256, b2 + l * 128, h2, sums2, N);
        bn_coef<<<dim3(1), dim3(128), 0, stream>>>(
            sums2, gamma + l * 128, beta + l * 128, coef, invN);
        if (l < LAYERS - 1)
            bn_apply_bf16<<<dim3(1024), blk, 0, stream>>>(h2, coef, hb, total4);
    }

    // --- two-stage mean pool + folded final BN + head ---
    hipMemsetAsync(pooled, 0, NGRAPHS * 128 * 4, stream);
    pool_part<<<dim3(784), blk, 0, stream>>>(h2, batch, pooled, N);
    head_final<<<dim3(NGRAPHS), dim3(128), 0, stream>>>(
        pooled, batch, coef, Wp, bp, (float*)d_out, N);
}

// Round 9
// 593.450 us; speedup vs baseline: 3.4362x; 1.1145x over previous
//
#include <hip/hip_runtime.h>
#include <stdint.h>

#define EMB 128
#define LAYERS 3
#define NGRAPHS 64
#define BN_EPS 1e-5f

typedef short short8 __attribute__((ext_vector_type(8)));
typedef float float4v __attribute__((ext_vector_type(4)));
typedef unsigned short ushort4v __attribute__((ext_vector_type(4)));

__device__ __forceinline__ unsigned short f2bf(float f) {
    union { float f; unsigned int i; } v; v.f = f;
    unsigned int x = v.i;
    unsigned int r = x + 0x7FFFu + ((x >> 16) & 1u);
    return (unsigned short)(r >> 16);
}
__device__ __forceinline__ float bflo(unsigned int u) {
    union { unsigned int i; float f; } v; v.i = u << 16; return v.f;
}
__device__ __forceinline__ float bfhi(unsigned int u) {
    union { unsigned int i; float f; } v; v.i = u & 0xffff0000u; return v.f;
}
__device__ __forceinline__ unsigned int packbf(float a, float b) {
    return (unsigned int)f2bf(a) | ((unsigned int)f2bf(b) << 16);
}

// f32 -> bf16 (RNE), three concatenated segments in one dispatch
__global__ __launch_bounds__(256) void conv_bf16_3(
    const float* __restrict__ a, unsigned short* __restrict__ oa, int na,
    const float* __restrict__ b, unsigned short* __restrict__ ob, int nb,
    const float* __restrict__ c, unsigned short* __restrict__ oc, int nc)
{
    int i = blockIdx.x * 256 + threadIdx.x;
    int stride = gridDim.x * 256;
    for (int t = i; t < na + nb + nc; t += stride) {
        if (t < na) oa[t] = f2bf(a[t]);
        else if (t < na + nb) ob[t - na] = f2bf(b[t - na]);
        else oc[t - na - nb] = f2bf(c[t - na - nb]);
    }
}

// ---------------------------------------------------------------------------
// GEMM (input embedding only): C = A[M,K] @ B[Ntot,K]^T + bias
// ---------------------------------------------------------------------------
template<int K, bool A_IS_BF16, bool RELU, bool OUT_BF16>
__global__ __launch_bounds__(256) void gemm_bt(
    const void* __restrict__ Av, const unsigned short* __restrict__ B,
    const float* __restrict__ bias, void* __restrict__ Cv,
    int M, int Ntot)
{
    const int wave = threadIdx.x >> 6;
    const int lane = threadIdx.x & 63;
    const int q    = lane >> 4;
    const int ln   = lane & 15;
    const int m_base = blockIdx.x * 64 + wave * 16;
    const int n_base = blockIdx.y * 64;

    float4v acc[4];
#pragma unroll
    for (int i = 0; i < 4; ++i) acc[i] = (float4v){0.f, 0.f, 0.f, 0.f};

    int mrow = m_base + ln;
    if (mrow >= M) mrow = M - 1;

    const int KSTEPS = K / 32;
#pragma unroll
    for (int ks = 0; ks < KSTEPS; ++ks) {
        const int k0 = ks * 32 + q * 8;
        short8 afrag;
        if constexpr (A_IS_BF16) {
            const unsigned short* A = (const unsigned short*)Av;
            afrag = *reinterpret_cast<const short8*>(A + (size_t)mrow * K + k0);
        } else {
            const float* A = (const float*)Av;
            const float4v* p = reinterpret_cast<const float4v*>(A + (size_t)mrow * K + k0);
            float4v f0 = p[0], f1 = p[1];
            afrag[0] = (short)f2bf(f0[0]); afrag[1] = (short)f2bf(f0[1]);
            afrag[2] = (short)f2bf(f0[2]); afrag[3] = (short)f2bf(f0[3]);
            afrag[4] = (short)f2bf(f1[0]); afrag[5] = (short)f2bf(f1[1]);
            afrag[6] = (short)f2bf(f1[2]); afrag[7] = (short)f2bf(f1[3]);
        }
#pragma unroll
        for (int nt = 0; nt < 4; ++nt) {
            const short8 bfrag = *reinterpret_cast<const short8*>(
                B + (size_t)(n_base + nt * 16 + ln) * K + k0);
            acc[nt] = __builtin_amdgcn_mfma_f32_16x16x32_bf16(afrag, bfrag, acc[nt], 0, 0, 0);
        }
    }

#pragma unroll
    for (int nt = 0; nt < 4; ++nt) {
        const int n = n_base + nt * 16 + ln;
        const float bv = bias[n];
#pragma unroll
        for (int r = 0; r < 4; ++r) {
            const int m = m_base + q * 4 + r;
            if (m < M) {
                float v = acc[nt][r] + bv;
                if constexpr (RELU) v = v > 0.f ? v : 0.f;
                if constexpr (OUT_BF16)
                    ((unsigned short*)Cv)[(size_t)m * Ntot + n] = f2bf(v);
                else
                    ((float*)Cv)[(size_t)m * Ntot + n] = v;
            }
        }
    }
}

// ---------------------------------------------------------------------------
// Fused MLP v3: weights register-resident, node-streaming.
// Block = 512 thr (8 waves). Wave w holds W1 rows [w*32, w*32+32) (2 ct tiles)
// and W2 rows [w*16, w*16+16) (1 ct tile) in VGPRs, loaded ONCE.
// Grid-stride over 16-node tiles: ag tile -> LDS, stage1 -> Y^T in LDS,
// stage2 -> h2 + striped BN partial stats. Math identical to r7 (verified).
// ---------------------------------------------------------------------------
__global__ __launch_bounds__(512) void fused_mlp(
    const unsigned short* __restrict__ ag, const unsigned short* __restrict__ W1,
    const float* __restrict__ b1, const unsigned short* __restrict__ W2,
    const float* __restrict__ b2, float* __restrict__ h2,
    float* __restrict__ sums2, int M, int ntiles)
{
    __shared__ unsigned short ag_lds[16 * 136];
    __shared__ unsigned short Ylds[16 * 264];
    const int tid = threadIdx.x;
    const int wave = tid >> 6, lane = tid & 63;
    const int q = lane >> 4, ln = lane & 15;
    const int k0 = q * 8;
    float* slice = sums2 + (size_t)(blockIdx.x & 31) * 256;

    // --- load resident weight fragments (once per block) ---
    short8 w1f[2][4], w2f[8];
#pragma unroll
    for (int c = 0; c < 2; ++c) {
        const int ct = wave * 2 + c;
#pragma unroll
        for (int ks = 0; ks < 4; ++ks)
            w1f[c][ks] = *reinterpret_cast<const short8*>(
                W1 + (size_t)(ct * 16 + ln) * 128 + ks * 32 + k0);
    }
#pragma unroll
    for (int ks = 0; ks < 8; ++ks)
        w2f[ks] = *reinterpret_cast<const short8*>(
            W2 + (size_t)(wave * 16 + ln) * 256 + ks * 32 + k0);
    float4v b1v[2];
    b1v[0] = *reinterpret_cast<const float4v*>(b1 + (wave * 2) * 16 + q * 4);
    b1v[1] = *reinterpret_cast<const float4v*>(b1 + (wave * 2 + 1) * 16 + q * 4);
    const float4v b2v = *reinterpret_cast<const float4v*>(b2 + wave * 16 + q * 4);

    for (int t = blockIdx.x; t < ntiles; t += gridDim.x) {
        const int nbase = t * 16;
        __syncthreads();   // previous iteration's LDS readers done
        // coop-load ag tile: 16 nodes x 128 ch bf16, node stride 136
        {
            const int nd = tid >> 5, ch = (tid & 31) * 4;
            int ng = nbase + nd; if (ng >= M) ng = M - 1;
            *reinterpret_cast<uint2*>(&ag_lds[nd * 136 + ch]) =
                *reinterpret_cast<const uint2*>(ag + (size_t)ng * 128 + ch);
        }
        __syncthreads();

        // stage 1: Y^T tile (channels x nodes)
        short8 agf[4];
#pragma unroll
        for (int ks = 0; ks < 4; ++ks)
            agf[ks] = *reinterpret_cast<const short8*>(
                &ag_lds[ln * 136 + ks * 32 + k0]);
#pragma unroll
        for (int c = 0; c < 2; ++c) {
            float4v acc = (float4v){0.f, 0.f, 0.f, 0.f};
#pragma unroll
            for (int ks = 0; ks < 4; ++ks)
                acc = __builtin_amdgcn_mfma_f32_16x16x32_bf16(
                    w1f[c][ks], agf[ks], acc, 0, 0, 0);
            const int c0 = (wave * 2 + c) * 16 + q * 4;
            ushort4v pk;
            pk[0] = f2bf(fmaxf(acc[0] + b1v[c][0], 0.f));
            pk[1] = f2bf(fmaxf(acc[1] + b1v[c][1], 0.f));
            pk[2] = f2bf(fmaxf(acc[2] + b1v[c][2], 0.f));
            pk[3] = f2bf(fmaxf(acc[3] + b1v[c][3], 0.f));
            *reinterpret_cast<ushort4v*>(&Ylds[ln * 264 + c0]) = pk;
        }
        __syncthreads();

        // stage 2: h2 tile
        short8 yf[8];
#pragma unroll
        for (int ks = 0; ks < 8; ++ks)
            yf[ks] = *reinterpret_cast<const short8*>(
                &Ylds[ln * 264 + ks * 32 + k0]);
        float4v acc = (float4v){0.f, 0.f, 0.f, 0.f};
#pragma unroll
        for (int ks = 0; ks < 8; ++ks)
            acc = __builtin_amdgcn_mfma_f32_16x16x32_bf16(
                w2f[ks], yf[ks], acc, 0, 0, 0);
        const int node = nbase + ln;
        const bool valid = (node < M);
        const int c0 = wave * 16 + q * 4;
        float4v v;
        v[0] = acc[0] + b2v[0]; v[1] = acc[1] + b2v[1];
        v[2] = acc[2] + b2v[2]; v[3] = acc[3] + b2v[3];
        if (valid)
            *reinterpret_cast<float4v*>(h2 + (size_t)node * 128 + c0) = v;

        float s[4], s2[4];
#pragma unroll
        for (int r = 0; r < 4; ++r) {
            const float x = valid ? v[r] : 0.f;
            s[r] = x; s2[r] = x * x;
        }
#pragma unroll
        for (int off = 1; off < 16; off <<= 1) {
#pragma unroll
            for (int r = 0; r < 4; ++r) {
                s[r]  += __shfl_xor(s[r],  off);
                s2[r] += __shfl_xor(s2[r], off);
            }
        }
        if (ln == 0) {
#pragma unroll
            for (int r = 0; r < 4; ++r) {
                atomicAdd(&slice[c0 + r], s[r]);
                atomicAdd(&slice[128 + c0 + r], s2[r]);
            }
        }
    }
}

// ---------------------------------------------------------------------------
// Fold 32 striped stat slices into per-channel BN (scale, shift)
// ---------------------------------------------------------------------------
__global__ __launch_bounds__(128) void bn_coef(
    const float* __restrict__ sums2, const float* __restrict__ gamma,
    const float* __restrict__ beta, float* __restrict__ coef, float invN)
{
    const int c = threadIdx.x;
    float s = 0.f, ss = 0.f;
    for (int k = 0; k < 32; ++k) {
        s  += sums2[k * 256 + c];
        ss += sums2[k * 256 + 128 + c];
    }
    float mu = s * invN;
    float var = ss * invN - mu * mu;
    float sc = gamma[c] * rsqrtf(fmaxf(var, 0.f) + BN_EPS);
    coef[c] = sc;
    coef[128 + c] = beta[c] - mu * sc;
}

// ---------------------------------------------------------------------------
// CSR build: histogram, 3-phase parallel scan, fill (src, edge-id)
// ---------------------------------------------------------------------------
__global__ __launch_bounds__(256) void hist_kernel(
    const int* __restrict__ ei, int* __restrict__ deg_cnt, int E)
{
    int e = blockIdx.x * 256 + threadIdx.x;
    if (e < E) atomicAdd(&deg_cnt[ei[E + e]], 1);
}

__global__ __launch_bounds__(256) void scan_part(
    const int* __restrict__ deg, int* __restrict__ blocksum, int n)
{
    int i = blockIdx.x * 256 + threadIdx.x;
    int v = (i < n) ? deg[i] : 0;
    const int lane = threadIdx.x & 63;
#pragma unroll
    for (int off = 32; off > 0; off >>= 1) v += __shfl_down(v, off);
    __shared__ int ws[4];
    if (lane == 0) ws[threadIdx.x >> 6] = v;
    __syncthreads();
    if (threadIdx.x == 0)
        blocksum[blockIdx.x] = ws[0] + ws[1] + ws[2] + ws[3];
}

__global__ __launch_bounds__(256) void scan_top(
    int* __restrict__ blocksum, int nblk)
{
    const int t = threadIdx.x;
    int v = (t < nblk) ? blocksum[t] : 0;
    const int lane = t & 63, wv = t >> 6;
    int iv = v;
#pragma unroll
    for (int off = 1; off < 64; off <<= 1) {
        int u = __shfl_up(iv, off);
        if (lane >= off) iv += u;
    }
    __shared__ int ws[4];
    if (lane == 63) ws[wv] = iv;
    __syncthreads();
    int woff = 0;
    for (int j = 0; j < wv; ++j) woff += ws[j];
    if (t < nblk) blocksum[t] = woff + iv - v;
}

__global__ __launch_bounds__(256) void scan_emit(
    const int* __restrict__ deg, const int* __restrict__ blockoff,
    int* __restrict__ rowptr, int* __restrict__ wp, int n)
{
    int i = blockIdx.x * 256 + threadIdx.x;
    int v = (i < n) ? deg[i] : 0;
    const int lane = threadIdx.x & 63, wv = threadIdx.x >> 6;
    int iv = v;
#pragma unroll
    for (int off = 1; off < 64; off <<= 1) {
        int u = __shfl_up(iv, off);
        if (lane >= off) iv += u;
    }
    __shared__ int ws[4];
    if (lane == 63) ws[wv] = iv;
    __syncthreads();
    int woff = blockoff[blockIdx.x];
    for (int j = 0; j < wv; ++j) woff += ws[j];
    int ex = woff + iv - v;
    if (i < n) { rowptr[i] = ex; wp[i] = ex; }
    if (i == n - 1) rowptr[n] = ex + v;
}

__global__ __launch_bounds__(256) void fill_kernel(
    const int* __restrict__ ei, int* __restrict__ wp,
    int2* __restrict__ adj, int E)
{
    int e = blockIdx.x * 256 + threadIdx.x;
    if (e < E) {
        int dst = ei[E + e];
        int slot = atomicAdd(&wp[dst], 1);
        adj[slot] = make_int2(ei[e], e);
    }
}

// ---------------------------------------------------------------------------
// mom[n][k] = sum of eattr over in-edges (gather, no atomics)
// ---------------------------------------------------------------------------
__global__ __launch_bounds__(256) void mom_gather(
    const int2* __restrict__ adj, const int* __restrict__ rowptr,
    const float* __restrict__ eattr, float* __restrict__ mom, int N)
{
    const int lane = threadIdx.x & 63;
    const int gwave = (blockIdx.x * 256 + threadIdx.x) >> 6;
    const int nwaves = (gridDim.x * 256) >> 6;
    const int j = lane >> 4, k = lane & 15;
    for (int n = gwave; n < N; n += nwaves) {
        const int s = rowptr[n], e = rowptr[n + 1];
        float acc = 0.f;
        for (int p = s + j; p < e; p += 4) {
            const int eid = adj[p].y;
            acc += eattr[(size_t)eid * 16 + k];
        }
        acc += __shfl_xor(acc, 16);
        acc += __shfl_xor(acc, 32);
        if (lane < 16) mom[(size_t)n * 16 + lane] = acc;
    }
}

// ---------------------------------------------------------------------------
// Gather aggregation over bf16 h:
// ag[n] = bf16( h[n] + Σ_in h[src] + be*(deg+1) + We·mom[n] )
// ---------------------------------------------------------------------------
__global__ __launch_bounds__(256) void aggregate_kernel(
    const unsigned short* __restrict__ h, const int2* __restrict__ adj,
    const int* __restrict__ rowptr, const float* __restrict__ mom,
    const float* __restrict__ We, const float* __restrict__ be,
    unsigned short* __restrict__ ag, int N)
{
    const int lane = threadIdx.x & 63;
    const int gwave = (blockIdx.x * 256 + threadIdx.x) >> 6;
    const int nwaves = (gridDim.x * 256) >> 6;
    const int c0 = 2 * lane;

    float w0[16], w1[16];
#pragma unroll
    for (int k = 0; k < 16; ++k) {
        w0[k] = We[c0 * 16 + k];
        w1[k] = We[(c0 + 1) * 16 + k];
    }
    const float b0 = be[c0], b1 = be[c0 + 1];

    for (int n = gwave; n < N; n += nwaves) {
        const int s = rowptr[n], e = rowptr[n + 1];
        unsigned int self = *reinterpret_cast<const unsigned int*>(
            h + (size_t)n * 128 + c0);
        float ax = bflo(self), ay = bfhi(self);
        float mval = (lane < 16) ? mom[(size_t)n * 16 + lane] : 0.f;

        int p = s;
        for (; p + 8 <= e; p += 8) {
            int s0 = adj[p].x, s1 = adj[p+1].x, s2 = adj[p+2].x, s3 = adj[p+3].x;
            int s4 = adj[p+4].x, s5 = adj[p+5].x, s6 = adj[p+6].x, s7 = adj[p+7].x;
            unsigned int v0 = *reinterpret_cast<const unsigned int*>(h + (size_t)s0 * 128 + c0);
            unsigned int v1 = *reinterpret_cast<const unsigned int*>(h + (size_t)s1 * 128 + c0);
            unsigned int v2 = *reinterpret_cast<const unsigned int*>(h + (size_t)s2 * 128 + c0);
            unsigned int v3 = *reinterpret_cast<const unsigned int*>(h + (size_t)s3 * 128 + c0);
            unsigned int v4 = *reinterpret_cast<const unsigned int*>(h + (size_t)s4 * 128 + c0);
            unsigned int v5 = *reinterpret_cast<const unsigned int*>(h + (size_t)s5 * 128 + c0);
            unsigned int v6 = *reinterpret_cast<const unsigned int*>(h + (size_t)s6 * 128 + c0);
            unsigned int v7 = *reinterpret_cast<const unsigned int*>(h + (size_t)s7 * 128 + c0);
            ax += bflo(v0) + bflo(v1) + bflo(v2) + bflo(v3)
                + bflo(v4) + bflo(v5) + bflo(v6) + bflo(v7);
            ay += bfhi(v0) + bfhi(v1) + bfhi(v2) + bfhi(v3)
                + bfhi(v4) + bfhi(v5) + bfhi(v6) + bfhi(v7);
        }
        for (; p < e; ++p) {
            int sv = adj[p].x;
            unsigned int v = *reinterpret_cast<const unsigned int*>(
                h + (size_t)sv * 128 + c0);
            ax += bflo(v); ay += bfhi(v);
        }

        const float degp1 = (float)(e - s + 1);
        float d0 = b0 * degp1, d1 = b1 * degp1;
#pragma unroll
        for (int k = 0; k < 16; ++k) {
            const float sk = __shfl(mval, k);
            d0 += w0[k] * sk; d1 += w1[k] * sk;
        }
        ax += d0; ay += d1;
        *reinterpret_cast<unsigned int*>(ag + (size_t)n * 128 + c0) = packbf(ax, ay);
    }
}

// ---------------------------------------------------------------------------
// BN apply + relu -> bf16 h  (uses precomputed coef)
// ---------------------------------------------------------------------------
__global__ __launch_bounds__(256) void bn_apply_bf16(
    const float* __restrict__ h2, const float* __restrict__ coef,
    unsigned short* __restrict__ h, int total4)
{
    int tid = blockIdx.x * 256 + threadIdx.x;
    int c4 = (tid * 4) & 127;
    float sc[4], sh[4];
#pragma unroll
    for (int j = 0; j < 4; ++j) {
        sc[j] = coef[c4 + j];
        sh[j] = coef[128 + c4 + j];
    }
    int stride = gridDim.x * 256;
    for (int i = tid; i < total4; i += stride) {
        float4v v = reinterpret_cast<const float4v*>(h2)[i];
        float x0 = fmaxf(sc[0] * v[0] + sh[0], 0.f);
        float x1 = fmaxf(sc[1] * v[1] + sh[1], 0.f);
        float x2 = fmaxf(sc[2] * v[2] + sh[2], 0.f);
        float x3 = fmaxf(sc[3] * v[3] + sh[3], 0.f);
        uint2 o; o.x = packbf(x0, x1); o.y = packbf(x2, x3);
        reinterpret_cast<uint2*>(h)[i] = o;
    }
}

// ---------------------------------------------------------------------------
// Pool stage 1: segmented sum over sorted batch keys
// ---------------------------------------------------------------------------
__global__ __launch_bounds__(256) void pool_part(
    const float* __restrict__ h2, const int* __restrict__ batch,
    float* __restrict__ pooled, int N)
{
    const int per = (N + gridDim.x - 1) / gridDim.x;
    const int start = blockIdx.x * per;
    const int end = min(start + per, N);
    if (start >= end) return;
    const int c = threadIdx.x & 127;
    const int sub = threadIdx.x >> 7;
    int g_cur = batch[start];
    float acc = 0.f;
    for (int n = start + sub; n < end; n += 2) {
        int g = batch[n];
        if (g != g_cur) {
            if (acc != 0.f) atomicAdd(&pooled[(size_t)g_cur * 128 + c], acc);
            acc = 0.f; g_cur = g;
        }
        acc += h2[(size_t)n * 128 + c];
    }
    if (acc != 0.f) atomicAdd(&pooled[(size_t)g_cur * 128 + c], acc);
}

// ---------------------------------------------------------------------------
// Pool stage 2: mean + folded final BN affine (coef) + head dot
// ---------------------------------------------------------------------------
__global__ __launch_bounds__(128) void head_final(
    const float* __restrict__ pooled, const int* __restrict__ batch,
    const float* __restrict__ coef, const float* __restrict__ Wp,
    const float* __restrict__ bp, float* __restrict__ out, int N)
{
    const int g = blockIdx.x;
    __shared__ int sb[2];
    if (threadIdx.x < 2) {
        int target = g + threadIdx.x;
        int lo = 0, hi = N;
        while (lo < hi) {
            int mid = (lo + hi) >> 1;
            if (batch[mid] < target) lo = mid + 1; else hi = mid;
        }
        sb[threadIdx.x] = lo;
    }
    __syncthreads();
    const float cntf = fmaxf((float)(sb[1] - sb[0]), 1.f);
    const int c = threadIdx.x;
    float m = pooled[(size_t)g * 128 + c] / cntf;
    float v = (coef[c] * m + coef[128 + c]) * Wp[c];
    const int lane = threadIdx.x & 63;
#pragma unroll
    for (int off = 32; off > 0; off >>= 1) v += __shfl_down(v, off);
    __shared__ float wsum[2];
    if (lane == 0) wsum[threadIdx.x >> 6] = v;
    __syncthreads();
    if (threadIdx.x == 0) out[g] = wsum[0] + wsum[1] + bp[0];
}

// ---------------------------------------------------------------------------
extern "C" void kernel_launch(void* const* d_in, const int* in_sizes, int n_in,
                              void* d_out, int out_size, void* d_ws, size_t ws_size,
                              hipStream_t stream)
{
    const float* x     = (const float*)d_in[0];
    const float* eattr = (const float*)d_in[1];
    const float* W0    = (const float*)d_in[2];
    const float* b0    = (const float*)d_in[3];
    const float* We    = (const float*)d_in[4];
    const float* be    = (const float*)d_in[5];
    const float* W1    = (const float*)d_in[6];
    const float* b1    = (const float*)d_in[7];
    const float* W2    = (const float*)d_in[8];
    const float* b2    = (const float*)d_in[9];
    const float* gamma = (const float*)d_in[10];
    const float* beta  = (const float*)d_in[11];
    const float* Wp    = (const float*)d_in[12];
    const float* bp    = (const float*)d_in[13];
    const int* ei    = (const int*)d_in[14];
    const int* batch = (const int*)d_in[15];

    const int N = in_sizes[0] / 32;   // 50000
    const int E = in_sizes[1] / 16;   // 800000

    char* ws = (char*)d_ws;
    size_t off = 0;
    auto alloc = [&](size_t bytes) { char* p = ws + off; off += (bytes + 255) & ~(size_t)255; return p; };
    unsigned short* hb = (unsigned short*)alloc((size_t)N * 128 * 2);
    unsigned short* ag = (unsigned short*)alloc((size_t)N * 128 * 2);
    float* h2 = (float*)alloc((size_t)N * 128 * 4);
    // deg_cnt / wp alias h2 (dead before first fused_mlp write)
    int* deg_cnt = (int*)h2;
    int* wp      = ((int*)h2) + N;
    float* sums2   = (float*)alloc(32 * 256 * 4);
    float* coef    = (float*)alloc(256 * 4);
    float* pooled  = (float*)alloc(NGRAPHS * 128 * 4);
    float* mom     = (float*)alloc((size_t)N * 16 * 4);
    unsigned short* W0bf = (unsigned short*)alloc(128 * 32 * 2);
    unsigned short* W1bf = (unsigned short*)alloc(3 * 256 * 128 * 2);
    unsigned short* W2bf = (unsigned short*)alloc(3 * 128 * 256 * 2);
    int* rowptr   = (int*)alloc(((size_t)N + 1) * 4);
    int* blocksum = (int*)alloc(256 * 4);
    int2* adj     = (int2*)alloc((size_t)E * 8);

    const dim3 blk(256);
    const int mblocks = (N + 63) / 64;
    const int ntiles = (N + 15) / 16;
    const int total4 = N * 32;
    const int eblocks = (E + 255) / 256;
    const int sblocks = (N + 255) / 256;   // <=256
    const float invN = 1.0f / (float)N;

    // --- CSR + edge-attr moments (once, reused by all layers) ---
    hipMemsetAsync(deg_cnt, 0, (size_t)N * 4, stream);
    hist_kernel<<<dim3(eblocks), blk, 0, stream>>>(ei, deg_cnt, E);
    scan_part<<<dim3(sblocks), blk, 0, stream>>>(deg_cnt, blocksum, N);
    scan_top<<<dim3(1), blk, 0, stream>>>(blocksum, sblocks);
    scan_emit<<<dim3(sblocks), blk, 0, stream>>>(deg_cnt, blocksum, rowptr, wp, N);
    fill_kernel<<<dim3(eblocks), blk, 0, stream>>>(ei, wp, adj, E);
    mom_gather<<<dim3(2048), blk, 0, stream>>>(adj, rowptr, eattr, mom, N);

    // --- weight pre-conversion ---
    conv_bf16_3<<<dim3(384), blk, 0, stream>>>(
        W0, W0bf, 128 * 32, W1, W1bf, 3 * 256 * 128, W2, W2bf, 3 * 128 * 256);

    // h = bf16(x @ W0^T + b0)
    gemm_bt<32, false, false, true><<<dim3(mblocks, 2), blk, 0, stream>>>(
        x, W0bf, b0, (void*)hb, N, 128);

    for (int l = 0; l < LAYERS; ++l) {
        hipMemsetAsync(sums2, 0, 32 * 256 * 4, stream);
        aggregate_kernel<<<dim3(2048), blk, 0, stream>>>(
            hb, adj, rowptr, mom, We + l * 128 * 16, be + l * 128, ag, N);
        fused_mlp<<<dim3(640), dim3(512), 0, stream>>>(
            ag, W1bf + l * 256 * 128, b1 + l * 256,
            W2bf + l * 128 * 256, b2 + l * 128, h2, sums2, N, ntiles);
        bn_coef<<<dim3(1), dim3(128), 0, stream>>>(
            sums2, gamma + l * 128, beta + l * 128, coef, invN);
        if (l < LAYERS - 1)
            bn_apply_bf16<<<dim3(1024), blk, 0, stream>>>(h2, coef, hb, total4);
    }

    // --- two-stage mean pool + folded final BN + head ---
    hipMemsetAsync(pooled, 0, NGRAPHS * 128 * 4, stream);
    pool_part<<<dim3(784), blk, 0, stream>>>(h2, batch, pooled, N);
    head_final<<<dim3(NGRAPHS), dim3(128), 0, stream>>>(
        pooled, batch, coef, Wp, bp, (float*)d_out, N);
}